// Round 13
// baseline (254.740 us; speedup 1.0000x reference)
//
#include <hip/hip_runtime.h>

#define D 128
typedef __attribute__((ext_vector_type(8))) short short8;
typedef __attribute__((ext_vector_type(4))) float f32x4;

__device__ __forceinline__ float leaky(float x){ return x >= 0.f ? x : 0.01f*x; }
__device__ __forceinline__ unsigned short f2bf(float x){
    unsigned u = __float_as_uint(x);
    u = (u + 0x7fffu + ((u>>16)&1u)) >> 16;
    return (unsigned short)u;
}
__device__ __forceinline__ short8 pack8m(f32x4 a, f32x4 b){
    short8 s;
    s[0]=(short)f2bf(a[0]); s[1]=(short)f2bf(a[1]);
    s[2]=(short)f2bf(a[2]); s[3]=(short)f2bf(a[3]);
    s[4]=(short)f2bf(b[0]); s[5]=(short)f2bf(b[1]);
    s[6]=(short)f2bf(b[2]); s[7]=(short)f2bf(b[3]);
    return s;
}

// fold attention vectors: v[0:128)=W_att^T a_src, v[128:256)=W_att^T a_dst, v[256..257]=b·a
__global__ void k_prep(const float* __restrict__ Ww, const float* __restrict__ Wb,
                       const float* __restrict__ a, float* __restrict__ v){
    int i = threadIdx.x; if(i >= 128) return;
    float vs=0.f, vd=0.f;
    for (int o=0;o<D;++o){ float w = Ww[o*D+i]; vs = fmaf(w, a[o], vs); vd = fmaf(w, a[D+o], vd); }
    v[i]=vs; v[D+i]=vd;
    if(i==0){
        float cs=0.f,cd=0.f;
        for(int o=0;o<D;++o){ cs=fmaf(Wb[o],a[o],cs); cd=fmaf(Wb[o],a[D+o],cd); }
        v[256]=cs; v[257]=cd;
    }
}

// H_perm = bf16(F @ W1^T + b1) (permuted c' = (c&15)*8 + (c>>4)) + attention scalars ss/sd
// W1 consumed as fp32, converted in-register once per wave.
__global__ __launch_bounds__(256) void k_msgscal(const float* __restrict__ F,
        const float* __restrict__ W1, const float* __restrict__ b1,
        const float* __restrict__ v, unsigned short* __restrict__ Hp,
        float* __restrict__ ss, float* __restrict__ sd, int N){
    const int lane = threadIdx.x & 63;
    const int wid  = blockIdx.x*4 + (threadIdx.x>>6);
    const int nw   = gridDim.x*4;
    const int t = lane & 15, g = lane >> 4;
    short8 wf[4][8];
    #pragma unroll
    for(int kk=0;kk<4;++kk)
      #pragma unroll
      for(int j=0;j<8;++j){
        const float* p = W1 + (size_t)(j*16+t)*D + kk*32 + g*8;
        wf[kk][j] = pack8m(*(const f32x4*)p, *(const f32x4*)(p+4));
      }
    float bb[8];
    #pragma unroll
    for(int j=0;j<8;++j) bb[j] = b1[j*16+t];
    const float c_s = v[256], c_d = v[257];
    const int Mt = (N+15)>>4;
    for(int rt = wid; rt < Mt; rt += nw){
        int row0 = rt*16 + t;
        int row = row0 < N ? row0 : N-1;
        const float* fr = F + (size_t)row*D + g*8;
        f32x4 acc[8];
        #pragma unroll
        for(int j=0;j<8;++j) acc[j] = (f32x4){0.f,0.f,0.f,0.f};
        float ds = 0.f, dd = 0.f;
        #pragma unroll
        for(int kk=0;kk<4;++kk){
            f32x4 lo = *(const f32x4*)(fr + kk*32);
            f32x4 hi = *(const f32x4*)(fr + kk*32 + 4);
            f32x4 vsl = *(const f32x4*)(v + kk*32 + g*8);
            f32x4 vsh = *(const f32x4*)(v + kk*32 + g*8 + 4);
            f32x4 vdl = *(const f32x4*)(v + D + kk*32 + g*8);
            f32x4 vdh = *(const f32x4*)(v + D + kk*32 + g*8 + 4);
            #pragma unroll
            for(int q=0;q<4;++q){
                ds = fmaf(lo[q], vsl[q], ds); ds = fmaf(hi[q], vsh[q], ds);
                dd = fmaf(lo[q], vdl[q], dd); dd = fmaf(hi[q], vdh[q], dd);
            }
            short8 af = pack8m(lo, hi);
            #pragma unroll
            for(int j=0;j<8;++j)
                acc[j] = __builtin_amdgcn_mfma_f32_16x16x32_bf16(af, wf[kk][j], acc[j], 0,0,0);
        }
        ds += __shfl_xor(ds,16); ds += __shfl_xor(ds,32);
        dd += __shfl_xor(dd,16); dd += __shfl_xor(dd,32);
        if(g==0 && row0 < N){ ss[row0] = ds + c_s; sd[row0] = dd + c_d; }
        #pragma unroll
        for(int r=0;r<4;++r){
            int rr = rt*16 + g*4 + r;
            if(rr < N){
                short8 h;
                #pragma unroll
                for(int j=0;j<8;++j) h[j] = (short)f2bf(acc[j][r] + bb[j]);
                *(short8*)(Hp + (size_t)rr*D + t*8) = h;
            }
        }
    }
}

// P1: per-block LDS histogram over coarse buckets (dst>>6); M[bucket][blk]
__global__ __launch_bounds__(256) void k_bcount(const int* __restrict__ dst,
        unsigned* __restrict__ M, int E, int NB, int CHUNK){
    __shared__ unsigned h[1600];
    for(int i=threadIdx.x;i<NB;i+=256) h[i]=0u;
    __syncthreads();
    int s = blockIdx.x*CHUNK;
    int e = s+CHUNK < E ? s+CHUNK : E;
    for(int i=s+(int)threadIdx.x;i<e;i+=256) atomicAdd(&h[((unsigned)dst[i])>>6],1u);
    __syncthreads();
    for(int j=threadIdx.x;j<NB;j+=256) M[(size_t)j*gridDim.x + blockIdx.x] = h[j];
}

// P2a: block sums of 4096-chunks
__global__ __launch_bounds__(256) void k_scanA(const unsigned* __restrict__ M,
        unsigned* __restrict__ bsum, int n){
    __shared__ unsigned lds[4];
    int base = blockIdx.x*4096 + threadIdx.x*16;
    unsigned s=0;
    #pragma unroll
    for(int k=0;k<16;++k){ int i=base+k; if(i<n) s+=M[i]; }
    #pragma unroll
    for(int o=1;o<64;o<<=1) s += __shfl_xor(s,o);
    if((threadIdx.x&63)==0) lds[threadIdx.x>>6]=s;
    __syncthreads();
    if(threadIdx.x==0) bsum[blockIdx.x] = lds[0]+lds[1]+lds[2]+lds[3];
}

// P2b: per-block local exclusive scan; block prefix = reduce of raw bsum[0..b) (nsb<=128)
__global__ __launch_bounds__(256) void k_scanC(const unsigned* __restrict__ M,
        const unsigned* __restrict__ bsum, unsigned* __restrict__ Msc, int n, int nsb){
    __shared__ unsigned lds[4];
    __shared__ unsigned ps[2];
    int t = threadIdx.x;
    unsigned pv = (t < nsb && t < (int)blockIdx.x) ? bsum[t] : 0u;
    #pragma unroll
    for(int o=1;o<64;o<<=1) pv += __shfl_xor(pv,o);
    if((t&63)==0 && t<128) ps[t>>6]=pv;
    int base = blockIdx.x*4096 + t*16;
    unsigned v[16]; unsigned tsum=0;
    #pragma unroll
    for(int k=0;k<16;++k){ int i=base+k; v[k]=(i<n)?M[i]:0u; tsum+=v[k]; }
    unsigned x=tsum;
    #pragma unroll
    for(int o=1;o<64;o<<=1){ unsigned y=__shfl_up(x,(unsigned)o); if((t&63)>=o) x+=y; }
    if((t&63)==63) lds[t>>6]=x;
    __syncthreads();
    unsigned run = ps[0]+ps[1];
    for(int w=0;w<(t>>6);++w) run += lds[w];
    run += (x - tsum);
    #pragma unroll
    for(int k=0;k<16;++k){ int i=base+k; if(i<n) Msc[i]=run; run+=v[k]; }
}

// P3: bucket-partition edges; per-edge exp-weight computed here (streaming, high TLP).
__global__ __launch_bounds__(256) void k_bscatter(const int* __restrict__ src,
        const int* __restrict__ dst, const unsigned* __restrict__ Msc,
        const float* __restrict__ ss, const float* __restrict__ sdv,
        uint2* __restrict__ ew, int E, int NB, int CHUNK){
    __shared__ unsigned hoff[1600];
    int blk = blockIdx.x, NBLKg = gridDim.x;
    for(int i=threadIdx.x;i<NB;i+=256) hoff[i] = Msc[(size_t)i*NBLKg + blk];
    __syncthreads();
    int s0 = blk*CHUNK;
    int e1 = s0+CHUNK < E ? s0+CHUNK : E;
    for(int i=s0+(int)threadIdx.x;i<e1;i+=256){
        int d = dst[i];
        int s = src[i];
        float w = __expf(leaky(ss[s] + sdv[d]));
        unsigned p = atomicAdd(&hoff[((unsigned)d)>>6], 1u);
        ew[p] = make_uint2(((unsigned)s<<6)|((unsigned)d&63u), __float_as_uint(w));
    }
}

// P4: per-bucket fine CSR (64 dsts): LDS count -> wave scan -> LDS-atomic rank.
__global__ __launch_bounds__(256) void k_fine(const uint2* __restrict__ ew,
        const unsigned* __restrict__ Msc, uint2* __restrict__ ewp,
        unsigned* __restrict__ offs, int N, int NB, int NBLKg, int E){
    __shared__ unsigned cA[64], cB[64], loff[64];
    __shared__ unsigned begS, endS;
    int b = blockIdx.x;
    int dbase = b<<6;
    if(threadIdx.x==0){
        begS = Msc[(size_t)b*NBLKg];
        endS = (b+1 < NB) ? Msc[(size_t)(b+1)*NBLKg] : (unsigned)E;
    }
    if(threadIdx.x<64){ cA[threadIdx.x]=0u; cB[threadIdx.x]=0u; }
    __syncthreads();
    const unsigned beg = begS, end = endS;
    for(unsigned i=beg+threadIdx.x; i<end; i+=256)
        atomicAdd(&cA[ew[i].x & 63u], 1u);
    __syncthreads();
    if(threadIdx.x<64){
        unsigned c = cA[threadIdx.x];
        unsigned x = c;
        #pragma unroll
        for(int o=1;o<64;o<<=1){ unsigned y = __shfl_up(x,(unsigned)o); if((int)threadIdx.x>=o) x += y; }
        loff[threadIdx.x] = x - c;
        int dd = dbase + (int)threadIdx.x;
        if(dd < N) offs[dd] = beg + x - c;
    }
    if(b==0 && threadIdx.x==64) offs[N] = (unsigned)E;
    if(b==0 && threadIdx.x>=80 && threadIdx.x<96)
        ewp[E + (threadIdx.x-80)] = make_uint2(0u, 0u);   // zero-weight pad
    __syncthreads();
    for(unsigned i=beg+threadIdx.x; i<end; i+=256){
        uint2 p = ew[i];
        unsigned dl = p.x & 63u;
        unsigned r = atomicAdd(&cB[dl], 1u);
        ewp[beg + loff[dl] + r] = make_uint2(p.x >> 6, p.y);
    }
}

__device__ __forceinline__ void fma8(float* acc, uint4 u, float w){
    acc[0]=fmaf(w,__uint_as_float(u.x<<16),acc[0]);
    acc[1]=fmaf(w,__uint_as_float(u.x&0xffff0000u),acc[1]);
    acc[2]=fmaf(w,__uint_as_float(u.y<<16),acc[2]);
    acc[3]=fmaf(w,__uint_as_float(u.y&0xffff0000u),acc[3]);
    acc[4]=fmaf(w,__uint_as_float(u.z<<16),acc[4]);
    acc[5]=fmaf(w,__uint_as_float(u.z&0xffff0000u),acc[5]);
    acc[6]=fmaf(w,__uint_as_float(u.w<<16),acc[6]);
    acc[7]=fmaf(w,__uint_as_float(u.w&0xffff0000u),acc[7]);
}

// fused gather: 4 edges/iter, 16 lanes/edge, 16B/lane; branchless pad-safe
// consume-then-refill double buffer
__global__ __launch_bounds__(256) void k_gather(const unsigned* __restrict__ off,
        const uint2* __restrict__ ewp, const unsigned short* __restrict__ Hp,
        float* __restrict__ out, int N){
    const int wv = threadIdx.x>>6, l = threadIdx.x&63;
    const int d = blockIdx.x*4 + wv;
    if(d>=N) return;
    const int g = l>>4, t = l&15;
    const unsigned kb = off[d], ke = off[d+1];
    const unsigned toff = (unsigned)t*16u;
    float acc[8];
    #pragma unroll
    for(int j=0;j<8;++j) acc[j]=0.f;
    float den = 0.f;

    unsigned e = kb + g;
    uint2 p0 = ewp[e];
    uint4 u0 = *(const uint4*)((const char*)Hp + ((p0.x<<8) + toff));
    uint2 p1 = ewp[e+4];
    uint4 u1 = *(const uint4*)((const char*)Hp + ((p1.x<<8) + toff));
    while(e < ke){
        float w0 = __uint_as_float(p0.y);
        fma8(acc, u0, w0);
        p0 = ewp[e+8];
        u0 = *(const uint4*)((const char*)Hp + ((p0.x<<8) + toff));
        float w1 = (e+4 < ke) ? __uint_as_float(p1.y) : 0.f;
        fma8(acc, u1, w1);
        p1 = ewp[e+12];
        u1 = *(const uint4*)((const char*)Hp + ((p1.x<<8) + toff));
        den += w0 + w1;
        e += 8;
    }
    #pragma unroll
    for(int j=0;j<8;++j){
        acc[j] += __shfl_xor(acc[j],16);
        acc[j] += __shfl_xor(acc[j],32);
    }
    den += __shfl_xor(den,16);
    den += __shfl_xor(den,32);
    float inv = 1.f/(den + 1e-9f);
    int c = g*32 + t;
    out[(size_t)d*D + c]      = acc[g*2]  * inv;
    out[(size_t)d*D + c + 16] = acc[g*2+1]* inv;
}

// out = leaky(f + h + (f*h)@W2^T + b2), in place on out; W2 fp32, converted in-register
__global__ __launch_bounds__(256) void k_final(const float* __restrict__ F,
        const float* __restrict__ W2, const float* __restrict__ b2,
        float* __restrict__ out, int N){
    const int lane = threadIdx.x & 63;
    const int wid  = blockIdx.x*4 + (threadIdx.x>>6);
    const int nw   = gridDim.x*4;
    const int t = lane & 15, g = lane >> 4;
    short8 wf[4][8];
    #pragma unroll
    for(int kk=0;kk<4;++kk)
      #pragma unroll
      for(int j=0;j<8;++j){
        const float* p = W2 + (size_t)(j*16+t)*D + kk*32 + g*8;
        wf[kk][j] = pack8m(*(const f32x4*)p, *(const f32x4*)(p+4));
      }
    float bb[8];
    #pragma unroll
    for(int j=0;j<8;++j) bb[j] = b2[j*16+t];
    const int Mt = (N+15)>>4;
    for(int rt = wid; rt < Mt; rt += nw){
        int row = rt*16 + t; if(row>=N) row = N-1;
        const float* fr = F   + (size_t)row*D + g*8;
        const float* hr = out + (size_t)row*D + g*8;
        f32x4 acc[8];
        #pragma unroll
        for(int j=0;j<8;++j) acc[j] = (f32x4){0.f,0.f,0.f,0.f};
        #pragma unroll
        for(int kk=0;kk<4;++kk){
            f32x4 flo = *(const f32x4*)(fr + kk*32);
            f32x4 fhi = *(const f32x4*)(fr + kk*32 + 4);
            f32x4 hlo = *(const f32x4*)(hr + kk*32);
            f32x4 hhi = *(const f32x4*)(hr + kk*32 + 4);
            short8 af = pack8m(flo*hlo, fhi*hhi);
            #pragma unroll
            for(int j=0;j<8;++j)
                acc[j] = __builtin_amdgcn_mfma_f32_16x16x32_bf16(af, wf[kk][j], acc[j], 0,0,0);
        }
        #pragma unroll
        for(int r=0;r<4;++r){
            int rr = rt*16 + g*4 + r;
            if(rr < N){
                #pragma unroll
                for(int j=0;j<8;++j){
                    int c = j*16 + t;
                    float f = F[(size_t)rr*D + c];
                    float h = out[(size_t)rr*D + c];
                    out[(size_t)rr*D + c] = leaky(f + h + acc[j][r] + bb[j]);
                }
            }
        }
    }
}

extern "C" void kernel_launch(void* const* d_in, const int* in_sizes, int n_in,
                              void* d_out, int out_size, void* d_ws, size_t ws_size,
                              hipStream_t stream) {
    const int*   idx  = (const int*)  d_in[0];   // (2,E)
    const float* F    = (const float*)d_in[1];   // (N,128)
    const float* Waw  = (const float*)d_in[3];
    const float* Wab  = (const float*)d_in[4];
    const float* W1w  = (const float*)d_in[5];
    const float* W1b  = (const float*)d_in[6];
    const float* W2w  = (const float*)d_in[7];
    const float* W2b  = (const float*)d_in[8];
    const float* a    = (const float*)d_in[9];
    float* out = (float*)d_out;

    const int E = in_sizes[0]/2;
    const int N = in_sizes[1]/D;
    const int* srcp = idx;
    const int* dstp = idx + E;

    const int NBLK = 256;
    const int CHUNK = (E + NBLK - 1)/NBLK;
    const int NB = (N + 63)/64;            // coarse buckets (<=1600)
    const int NT = NB*NBLK;
    const int NSB = (NT + 4095)/4096;      // <=128 by construction

    uint2*    ew   = (uint2*)d_ws;                          // E
    uint2*    ewp  = ew + E;                                // E+16
    unsigned short* Hp  = (unsigned short*)(ewp + E + 16);  // N*128 bf16
    float*    ss   = (float*)(Hp + (size_t)N*D);            // N
    float*    sd   = ss + N;                                // N
    float*    v    = sd + N;                                // 320
    unsigned* M    = (unsigned*)(v + 320);                  // NT
    unsigned* Msc  = M + NT;                                // NT+2
    unsigned* bsum = Msc + NT + 2;                          // NSB
    unsigned* offs = bsum + NSB + 2;                        // N+2

    const int Mt = (N+15)/16;
    const int GG = (Mt+7)/8;

    k_prep    <<<1, 128, 0, stream>>>(Waw, Wab, a, v);
    k_msgscal <<<GG, 256, 0, stream>>>(F, W1w, W1b, v, Hp, ss, sd, N);
    k_bcount  <<<NBLK, 256, 0, stream>>>(dstp, M, E, NB, CHUNK);
    k_scanA   <<<NSB, 256, 0, stream>>>(M, bsum, NT);
    k_scanC   <<<NSB, 256, 0, stream>>>(M, bsum, Msc, NT, NSB);
    k_bscatter<<<NBLK, 256, 0, stream>>>(srcp, dstp, Msc, ss, sd, ew, E, NB, CHUNK);
    k_fine    <<<NB, 256, 0, stream>>>(ew, Msc, ewp, offs, N, NB, NBLK, E);
    k_gather  <<<(N+3)/4, 256, 0, stream>>>(offs, ewp, Hp, out, N);
    k_final   <<<GG, 256, 0, stream>>>(F, W2w, W2b, out, N);
}

// Round 14
// 192.899 us; speedup vs baseline: 1.3206x; 1.3206x over previous
//
#include <hip/hip_runtime.h>

#define D 128
typedef __attribute__((ext_vector_type(8))) short short8;
typedef __attribute__((ext_vector_type(4))) float f32x4;

__device__ __forceinline__ float leaky(float x){ return x >= 0.f ? x : 0.01f*x; }
__device__ __forceinline__ unsigned short f2bf(float x){
    unsigned u = __float_as_uint(x);
    u = (u + 0x7fffu + ((u>>16)&1u)) >> 16;
    return (unsigned short)u;
}
__device__ __forceinline__ short8 pack8m(f32x4 a, f32x4 b){
    short8 s;
    s[0]=(short)f2bf(a[0]); s[1]=(short)f2bf(a[1]);
    s[2]=(short)f2bf(a[2]); s[3]=(short)f2bf(a[3]);
    s[4]=(short)f2bf(b[0]); s[5]=(short)f2bf(b[1]);
    s[6]=(short)f2bf(b[2]); s[7]=(short)f2bf(b[3]);
    return s;
}

// fold attention vectors + convert W1/W2 to bf16 (blocks 0..63 convert, block 64 folds)
__global__ void k_prep(const float* __restrict__ Ww, const float* __restrict__ Wb,
                       const float* __restrict__ a, float* __restrict__ v,
                       const float* __restrict__ W1, const float* __restrict__ W2,
                       unsigned short* __restrict__ W1b, unsigned short* __restrict__ W2b){
    int b = blockIdx.x;
    if(b < 64){
        int i = b*256 + threadIdx.x; // 0..16383
        W1b[i] = f2bf(W1[i]);
        W2b[i] = f2bf(W2[i]);
        return;
    }
    int i = threadIdx.x; if(i >= 128) return;
    float vs=0.f, vd=0.f;
    for (int o=0;o<D;++o){ float w = Ww[o*D+i]; vs = fmaf(w, a[o], vs); vd = fmaf(w, a[D+o], vd); }
    v[i]=vs; v[D+i]=vd;
    if(i==0){
        float cs=0.f,cd=0.f;
        for(int o=0;o<D;++o){ cs=fmaf(Wb[o],a[o],cs); cd=fmaf(Wb[o],a[D+o],cd); }
        v[256]=cs; v[257]=cd;
    }
}

// Fused: [blocks < GT] H_perm = bf16(F @ W1^T + b1) (permuted c'=(c&15)*8+(c>>4))
//        + attention scalars ss/sd. Weights staged in LDS (stride 136 -> 2-way conflict only).
//        [blocks >= GT] coarse bucket histogram (bcount) using the same LDS buffer.
__global__ __launch_bounds__(256) void k_msgscal(const float* __restrict__ F,
        const unsigned short* __restrict__ W1b, const float* __restrict__ b1,
        const float* __restrict__ v, unsigned short* __restrict__ Hp,
        float* __restrict__ ss, float* __restrict__ sd, int N,
        const int* __restrict__ dst, unsigned* __restrict__ M,
        int E, int GT, int CHUNK, int NB){
    __shared__ __align__(16) unsigned short Wlds[17408];   // 128 rows x 136 halfwords
    if((int)blockIdx.x >= GT){
        unsigned* h = (unsigned*)Wlds;                      // 1600 x 4B overlay
        for(int i=threadIdx.x;i<NB;i+=256) h[i]=0u;
        __syncthreads();
        int blk = (int)blockIdx.x - GT;
        int s = blk*CHUNK;
        int e = s+CHUNK < E ? s+CHUNK : E;
        for(int i=s+(int)threadIdx.x;i<e;i+=256) atomicAdd(&h[((unsigned)dst[i])>>6],1u);
        __syncthreads();
        for(int j=threadIdx.x;j<NB;j+=256) M[(size_t)j*256 + blk] = h[j];
        return;
    }
    // stage W1 (bf16 [128][128]) -> LDS [128][136]
    #pragma unroll
    for(int k=0;k<8;++k){
        int idx = ((int)threadIdx.x + k*256)*8;     // 0..16376
        int row = idx >> 7, col = idx & 127;
        *(short8*)(&Wlds[row*136 + col]) = *(const short8*)(W1b + idx);
    }
    __syncthreads();
    const int lane = threadIdx.x & 63, wv = threadIdx.x>>6;
    const int t = lane & 15, g = lane >> 4;
    float bb[8];
    #pragma unroll
    for(int j=0;j<8;++j) bb[j] = b1[j*16+t];
    const float c_s = v[256], c_d = v[257];
    const int Mt = (N+15)>>4;
    for(int rt = (int)blockIdx.x*4 + wv; rt < Mt; rt += GT*4){
        int row0 = rt*16 + t;
        int row = row0 < N ? row0 : N-1;
        const float* fr = F + (size_t)row*D + g*8;
        f32x4 acc[8];
        #pragma unroll
        for(int j=0;j<8;++j) acc[j] = (f32x4){0.f,0.f,0.f,0.f};
        float ds = 0.f, dd = 0.f;
        #pragma unroll
        for(int kk=0;kk<4;++kk){
            f32x4 lo = *(const f32x4*)(fr + kk*32);
            f32x4 hi = *(const f32x4*)(fr + kk*32 + 4);
            f32x4 vsl = *(const f32x4*)(v + kk*32 + g*8);
            f32x4 vsh = *(const f32x4*)(v + kk*32 + g*8 + 4);
            f32x4 vdl = *(const f32x4*)(v + D + kk*32 + g*8);
            f32x4 vdh = *(const f32x4*)(v + D + kk*32 + g*8 + 4);
            #pragma unroll
            for(int q=0;q<4;++q){
                ds = fmaf(lo[q], vsl[q], ds); ds = fmaf(hi[q], vsh[q], ds);
                dd = fmaf(lo[q], vdl[q], dd); dd = fmaf(hi[q], vdh[q], dd);
            }
            short8 af = pack8m(lo, hi);
            #pragma unroll
            for(int j=0;j<8;++j){
                short8 wfj = *(const short8*)(&Wlds[(j*16+t)*136 + kk*32 + g*8]);
                acc[j] = __builtin_amdgcn_mfma_f32_16x16x32_bf16(af, wfj, acc[j], 0,0,0);
            }
        }
        ds += __shfl_xor(ds,16); ds += __shfl_xor(ds,32);
        dd += __shfl_xor(dd,16); dd += __shfl_xor(dd,32);
        if(g==0 && row0 < N){ ss[row0] = ds + c_s; sd[row0] = dd + c_d; }
        #pragma unroll
        for(int r=0;r<4;++r){
            int rr = rt*16 + g*4 + r;
            if(rr < N){
                short8 h;
                #pragma unroll
                for(int j=0;j<8;++j) h[j] = (short)f2bf(acc[j][r] + bb[j]);
                *(short8*)(Hp + (size_t)rr*D + t*8) = h;
            }
        }
    }
}

// P2a: block sums of 4096-chunks
__global__ __launch_bounds__(256) void k_scanA(const unsigned* __restrict__ M,
        unsigned* __restrict__ bsum, int n){
    __shared__ unsigned lds[4];
    int base = blockIdx.x*4096 + threadIdx.x*16;
    unsigned s=0;
    #pragma unroll
    for(int k=0;k<16;++k){ int i=base+k; if(i<n) s+=M[i]; }
    #pragma unroll
    for(int o=1;o<64;o<<=1) s += __shfl_xor(s,o);
    if((threadIdx.x&63)==0) lds[threadIdx.x>>6]=s;
    __syncthreads();
    if(threadIdx.x==0) bsum[blockIdx.x] = lds[0]+lds[1]+lds[2]+lds[3];
}

// P2b: per-block local exclusive scan; block prefix = reduce of raw bsum[0..b) (nsb<=128)
__global__ __launch_bounds__(256) void k_scanC(const unsigned* __restrict__ M,
        const unsigned* __restrict__ bsum, unsigned* __restrict__ Msc, int n, int nsb){
    __shared__ unsigned lds[4];
    __shared__ unsigned ps[2];
    int t = threadIdx.x;
    unsigned pv = (t < nsb && t < (int)blockIdx.x) ? bsum[t] : 0u;
    #pragma unroll
    for(int o=1;o<64;o<<=1) pv += __shfl_xor(pv,o);
    if((t&63)==0 && t<128) ps[t>>6]=pv;
    int base = blockIdx.x*4096 + t*16;
    unsigned v[16]; unsigned tsum=0;
    #pragma unroll
    for(int k=0;k<16;++k){ int i=base+k; v[k]=(i<n)?M[i]:0u; tsum+=v[k]; }
    unsigned x=tsum;
    #pragma unroll
    for(int o=1;o<64;o<<=1){ unsigned y=__shfl_up(x,(unsigned)o); if((t&63)>=o) x+=y; }
    if((t&63)==63) lds[t>>6]=x;
    __syncthreads();
    unsigned run = ps[0]+ps[1];
    for(int w=0;w<(t>>6);++w) run += lds[w];
    run += (x - tsum);
    #pragma unroll
    for(int k=0;k<16;++k){ int i=base+k; if(i<n) Msc[i]=run; run+=v[k]; }
}

// P3: bucket-partition edges; per-edge exp-weight computed here (streaming, high TLP).
__global__ __launch_bounds__(256) void k_bscatter(const int* __restrict__ src,
        const int* __restrict__ dst, const unsigned* __restrict__ Msc,
        const float* __restrict__ ss, const float* __restrict__ sdv,
        uint2* __restrict__ ew, int E, int NB, int CHUNK){
    __shared__ unsigned hoff[1600];
    int blk = blockIdx.x, NBLKg = gridDim.x;
    for(int i=threadIdx.x;i<NB;i+=256) hoff[i] = Msc[(size_t)i*NBLKg + blk];
    __syncthreads();
    int s0 = blk*CHUNK;
    int e1 = s0+CHUNK < E ? s0+CHUNK : E;
    for(int i=s0+(int)threadIdx.x;i<e1;i+=256){
        int d = dst[i];
        int s = src[i];
        float w = __expf(leaky(ss[s] + sdv[d]));
        unsigned p = atomicAdd(&hoff[((unsigned)d)>>6], 1u);
        ew[p] = make_uint2(((unsigned)s<<6)|((unsigned)d&63u), __float_as_uint(w));
    }
}

// P4: per-bucket fine CSR (64 dsts): LDS count -> wave scan -> LDS-atomic rank.
__global__ __launch_bounds__(256) void k_fine(const uint2* __restrict__ ew,
        const unsigned* __restrict__ Msc, uint2* __restrict__ ewp,
        unsigned* __restrict__ offs, int N, int NB, int NBLKg, int E){
    __shared__ unsigned cA[64], cB[64], loff[64];
    __shared__ unsigned begS, endS;
    int b = blockIdx.x;
    int dbase = b<<6;
    if(threadIdx.x==0){
        begS = Msc[(size_t)b*NBLKg];
        endS = (b+1 < NB) ? Msc[(size_t)(b+1)*NBLKg] : (unsigned)E;
    }
    if(threadIdx.x<64){ cA[threadIdx.x]=0u; cB[threadIdx.x]=0u; }
    __syncthreads();
    const unsigned beg = begS, end = endS;
    for(unsigned i=beg+threadIdx.x; i<end; i+=256)
        atomicAdd(&cA[ew[i].x & 63u], 1u);
    __syncthreads();
    if(threadIdx.x<64){
        unsigned c = cA[threadIdx.x];
        unsigned x = c;
        #pragma unroll
        for(int o=1;o<64;o<<=1){ unsigned y = __shfl_up(x,(unsigned)o); if((int)threadIdx.x>=o) x += y; }
        loff[threadIdx.x] = x - c;
        int dd = dbase + (int)threadIdx.x;
        if(dd < N) offs[dd] = beg + x - c;
    }
    if(b==0 && threadIdx.x==64) offs[N] = (unsigned)E;
    if(b==0 && threadIdx.x>=80 && threadIdx.x<96)
        ewp[E + (threadIdx.x-80)] = make_uint2(0u, 0u);   // zero-weight pad
    __syncthreads();
    for(unsigned i=beg+threadIdx.x; i<end; i+=256){
        uint2 p = ew[i];
        unsigned dl = p.x & 63u;
        unsigned r = atomicAdd(&cB[dl], 1u);
        ewp[beg + loff[dl] + r] = make_uint2(p.x >> 6, p.y);
    }
}

__device__ __forceinline__ void fma8(float* acc, uint4 u, float w){
    acc[0]=fmaf(w,__uint_as_float(u.x<<16),acc[0]);
    acc[1]=fmaf(w,__uint_as_float(u.x&0xffff0000u),acc[1]);
    acc[2]=fmaf(w,__uint_as_float(u.y<<16),acc[2]);
    acc[3]=fmaf(w,__uint_as_float(u.y&0xffff0000u),acc[3]);
    acc[4]=fmaf(w,__uint_as_float(u.z<<16),acc[4]);
    acc[5]=fmaf(w,__uint_as_float(u.z&0xffff0000u),acc[5]);
    acc[6]=fmaf(w,__uint_as_float(u.w<<16),acc[6]);
    acc[7]=fmaf(w,__uint_as_float(u.w&0xffff0000u),acc[7]);
}

// fused gather: 4 edges/iter, 16 lanes/edge, 16B/lane; branchless pad-safe
// consume-then-refill double buffer
__global__ __launch_bounds__(256) void k_gather(const unsigned* __restrict__ off,
        const uint2* __restrict__ ewp, const unsigned short* __restrict__ Hp,
        float* __restrict__ out, int N){
    const int wv = threadIdx.x>>6, l = threadIdx.x&63;
    const int d = blockIdx.x*4 + wv;
    if(d>=N) return;
    const int g = l>>4, t = l&15;
    const unsigned kb = off[d], ke = off[d+1];
    const unsigned toff = (unsigned)t*16u;
    float acc[8];
    #pragma unroll
    for(int j=0;j<8;++j) acc[j]=0.f;
    float den = 0.f;

    unsigned e = kb + g;
    uint2 p0 = ewp[e];
    uint4 u0 = *(const uint4*)((const char*)Hp + ((p0.x<<8) + toff));
    uint2 p1 = ewp[e+4];
    uint4 u1 = *(const uint4*)((const char*)Hp + ((p1.x<<8) + toff));
    while(e < ke){
        float w0 = __uint_as_float(p0.y);
        fma8(acc, u0, w0);
        p0 = ewp[e+8];
        u0 = *(const uint4*)((const char*)Hp + ((p0.x<<8) + toff));
        float w1 = (e+4 < ke) ? __uint_as_float(p1.y) : 0.f;
        fma8(acc, u1, w1);
        p1 = ewp[e+12];
        u1 = *(const uint4*)((const char*)Hp + ((p1.x<<8) + toff));
        den += w0 + w1;
        e += 8;
    }
    #pragma unroll
    for(int j=0;j<8;++j){
        acc[j] += __shfl_xor(acc[j],16);
        acc[j] += __shfl_xor(acc[j],32);
    }
    den += __shfl_xor(den,16);
    den += __shfl_xor(den,32);
    float inv = 1.f/(den + 1e-9f);
    int c = g*32 + t;
    out[(size_t)d*D + c]      = acc[g*2]  * inv;
    out[(size_t)d*D + c + 16] = acc[g*2+1]* inv;
}

// out = leaky(f + h + (f*h)@W2^T + b2), in place on out; W2 (bf16) staged in LDS
__global__ __launch_bounds__(256) void k_final(const float* __restrict__ F,
        const unsigned short* __restrict__ W2b, const float* __restrict__ b2,
        float* __restrict__ out, int N, int GF){
    __shared__ __align__(16) unsigned short Wlds[17408];
    #pragma unroll
    for(int k=0;k<8;++k){
        int idx = ((int)threadIdx.x + k*256)*8;
        int row = idx >> 7, col = idx & 127;
        *(short8*)(&Wlds[row*136 + col]) = *(const short8*)(W2b + idx);
    }
    __syncthreads();
    const int lane = threadIdx.x & 63, wv = threadIdx.x>>6;
    const int t = lane & 15, g = lane >> 4;
    float bb[8];
    #pragma unroll
    for(int j=0;j<8;++j) bb[j] = b2[j*16+t];
    const int Mt = (N+15)>>4;
    for(int rt = (int)blockIdx.x*4 + wv; rt < Mt; rt += GF*4){
        int row = rt*16 + t; if(row>=N) row = N-1;
        const float* fr = F   + (size_t)row*D + g*8;
        const float* hr = out + (size_t)row*D + g*8;
        f32x4 acc[8];
        #pragma unroll
        for(int j=0;j<8;++j) acc[j] = (f32x4){0.f,0.f,0.f,0.f};
        #pragma unroll
        for(int kk=0;kk<4;++kk){
            f32x4 flo = *(const f32x4*)(fr + kk*32);
            f32x4 fhi = *(const f32x4*)(fr + kk*32 + 4);
            f32x4 hlo = *(const f32x4*)(hr + kk*32);
            f32x4 hhi = *(const f32x4*)(hr + kk*32 + 4);
            short8 af = pack8m(flo*hlo, fhi*hhi);
            #pragma unroll
            for(int j=0;j<8;++j){
                short8 wfj = *(const short8*)(&Wlds[(j*16+t)*136 + kk*32 + g*8]);
                acc[j] = __builtin_amdgcn_mfma_f32_16x16x32_bf16(af, wfj, acc[j], 0,0,0);
            }
        }
        #pragma unroll
        for(int r=0;r<4;++r){
            int rr = rt*16 + g*4 + r;
            if(rr < N){
                #pragma unroll
                for(int j=0;j<8;++j){
                    int c = j*16 + t;
                    float f = F[(size_t)rr*D + c];
                    float h = out[(size_t)rr*D + c];
                    out[(size_t)rr*D + c] = leaky(f + h + acc[j][r] + bb[j]);
                }
            }
        }
    }
}

extern "C" void kernel_launch(void* const* d_in, const int* in_sizes, int n_in,
                              void* d_out, int out_size, void* d_ws, size_t ws_size,
                              hipStream_t stream) {
    const int*   idx  = (const int*)  d_in[0];   // (2,E)
    const float* F    = (const float*)d_in[1];   // (N,128)
    const float* Waw  = (const float*)d_in[3];
    const float* Wab  = (const float*)d_in[4];
    const float* W1w  = (const float*)d_in[5];
    const float* W1b  = (const float*)d_in[6];
    const float* W2w  = (const float*)d_in[7];
    const float* W2b  = (const float*)d_in[8];
    const float* a    = (const float*)d_in[9];
    float* out = (float*)d_out;

    const int E = in_sizes[0]/2;
    const int N = in_sizes[1]/D;
    const int* srcp = idx;
    const int* dstp = idx + E;

    const int NBLK = 256;
    const int CHUNK = (E + NBLK - 1)/NBLK;
    const int NB = (N + 63)/64;            // coarse buckets (<=1600)
    const int NT = NB*NBLK;
    const int NSB = (NT + 4095)/4096;      // <=128 by construction

    uint2*    ew   = (uint2*)d_ws;                          // E
    uint2*    ewp  = ew + E;                                // E+16
    unsigned short* Hp  = (unsigned short*)(ewp + E + 16);  // N*128 bf16
    unsigned short* W1c = Hp + (size_t)N*D;                 // 16384
    unsigned short* W2c = W1c + 16384;                      // 16384
    float*    ss   = (float*)(W2c + 16384);                 // N
    float*    sd   = ss + N;                                // N
    float*    v    = sd + N;                                // 320
    unsigned* M    = (unsigned*)(v + 320);                  // NT
    unsigned* Msc  = M + NT;                                // NT+2
    unsigned* bsum = Msc + NT + 2;                          // NSB
    unsigned* offs = bsum + NSB + 2;                        // N+2

    const int Mt = (N+15)/16;
    const int GT = (Mt+3)/4;               // 1 tile per wave
    const int GF = GT;

    k_prep    <<<65, 256, 0, stream>>>(Waw, Wab, a, v, W1w, W2w, W1c, W2c);
    k_msgscal <<<GT+NBLK, 256, 0, stream>>>(F, W1c, W1b, v, Hp, ss, sd, N,
                                            dstp, M, E, GT, CHUNK, NB);
    k_scanA   <<<NSB, 256, 0, stream>>>(M, bsum, NT);
    k_scanC   <<<NSB, 256, 0, stream>>>(M, bsum, Msc, NT, NSB);
    k_bscatter<<<NBLK, 256, 0, stream>>>(srcp, dstp, Msc, ss, sd, ew, E, NB, CHUNK);
    k_fine    <<<NB, 256, 0, stream>>>(ew, Msc, ewp, offs, N, NB, NBLK, E);
    k_gather  <<<(N+3)/4, 256, 0, stream>>>(offs, ewp, Hp, out, N);
    k_final   <<<GF, 256, 0, stream>>>(F, W2c, W2b, out, N, GF);
}

// Round 15
// 185.683 us; speedup vs baseline: 1.3719x; 1.0389x over previous
//
#include <hip/hip_runtime.h>

#define D 128
#define CAP 2560
typedef __attribute__((ext_vector_type(8))) short short8;
typedef __attribute__((ext_vector_type(4))) float f32x4;

__device__ __forceinline__ float leaky(float x){ return x >= 0.f ? x : 0.01f*x; }
__device__ __forceinline__ unsigned short f2bf(float x){
    unsigned u = __float_as_uint(x);
    u = (u + 0x7fffu + ((u>>16)&1u)) >> 16;
    return (unsigned short)u;
}
__device__ __forceinline__ short8 pack8m(f32x4 a, f32x4 b){
    short8 s;
    s[0]=(short)f2bf(a[0]); s[1]=(short)f2bf(a[1]);
    s[2]=(short)f2bf(a[2]); s[3]=(short)f2bf(a[3]);
    s[4]=(short)f2bf(b[0]); s[5]=(short)f2bf(b[1]);
    s[6]=(short)f2bf(b[2]); s[7]=(short)f2bf(b[3]);
    return s;
}

// fold attention vectors + convert W1/W2 to bf16 (blocks 0..63 convert, block 64 folds)
__global__ void k_prep(const float* __restrict__ Ww, const float* __restrict__ Wb,
                       const float* __restrict__ a, float* __restrict__ v,
                       const float* __restrict__ W1, const float* __restrict__ W2,
                       unsigned short* __restrict__ W1b, unsigned short* __restrict__ W2b){
    int b = blockIdx.x;
    if(b < 64){
        int i = b*256 + threadIdx.x; // 0..16383
        W1b[i] = f2bf(W1[i]);
        W2b[i] = f2bf(W2[i]);
        return;
    }
    int i = threadIdx.x; if(i >= 128) return;
    float vs=0.f, vd=0.f;
    for (int o=0;o<D;++o){ float w = Ww[o*D+i]; vs = fmaf(w, a[o], vs); vd = fmaf(w, a[D+o], vd); }
    v[i]=vs; v[D+i]=vd;
    if(i==0){
        float cs=0.f,cd=0.f;
        for(int o=0;o<D;++o){ cs=fmaf(Wb[o],a[o],cs); cd=fmaf(Wb[o],a[D+o],cd); }
        v[256]=cs; v[257]=cd;
    }
}

// Fused: [blocks < GT] H_perm = bf16(F @ W1^T + b1) (permuted c'=(c&15)*8+(c>>4))
//        + attention scalars ss/sd. Weights staged in LDS (stride 136).
//        [blocks >= GT] coarse bucket histogram (bcount) using the same LDS buffer.
__global__ __launch_bounds__(256) void k_msgscal(const float* __restrict__ F,
        const unsigned short* __restrict__ W1b, const float* __restrict__ b1,
        const float* __restrict__ v, unsigned short* __restrict__ Hp,
        float* __restrict__ ss, float* __restrict__ sd, int N,
        const int* __restrict__ dst, unsigned* __restrict__ M,
        int E, int GT, int CHUNK, int NB){
    __shared__ __align__(16) unsigned short Wlds[17408];   // 128 rows x 136 halfwords
    if((int)blockIdx.x >= GT){
        unsigned* h = (unsigned*)Wlds;                      // 1600 x 4B overlay
        for(int i=threadIdx.x;i<NB;i+=256) h[i]=0u;
        __syncthreads();
        int blk = (int)blockIdx.x - GT;
        int s = blk*CHUNK;
        int e = s+CHUNK < E ? s+CHUNK : E;
        for(int i=s+(int)threadIdx.x;i<e;i+=256) atomicAdd(&h[((unsigned)dst[i])>>6],1u);
        __syncthreads();
        for(int j=threadIdx.x;j<NB;j+=256) M[(size_t)j*256 + blk] = h[j];
        return;
    }
    #pragma unroll
    for(int k=0;k<8;++k){
        int idx = ((int)threadIdx.x + k*256)*8;
        int row = idx >> 7, col = idx & 127;
        *(short8*)(&Wlds[row*136 + col]) = *(const short8*)(W1b + idx);
    }
    __syncthreads();
    const int lane = threadIdx.x & 63, wv = threadIdx.x>>6;
    const int t = lane & 15, g = lane >> 4;
    float bb[8];
    #pragma unroll
    for(int j=0;j<8;++j) bb[j] = b1[j*16+t];
    const float c_s = v[256], c_d = v[257];
    const int Mt = (N+15)>>4;
    for(int rt = (int)blockIdx.x*4 + wv; rt < Mt; rt += GT*4){
        int row0 = rt*16 + t;
        int row = row0 < N ? row0 : N-1;
        const float* fr = F + (size_t)row*D + g*8;
        f32x4 acc[8];
        #pragma unroll
        for(int j=0;j<8;++j) acc[j] = (f32x4){0.f,0.f,0.f,0.f};
        float ds = 0.f, dd = 0.f;
        #pragma unroll
        for(int kk=0;kk<4;++kk){
            f32x4 lo = *(const f32x4*)(fr + kk*32);
            f32x4 hi = *(const f32x4*)(fr + kk*32 + 4);
            f32x4 vsl = *(const f32x4*)(v + kk*32 + g*8);
            f32x4 vsh = *(const f32x4*)(v + kk*32 + g*8 + 4);
            f32x4 vdl = *(const f32x4*)(v + D + kk*32 + g*8);
            f32x4 vdh = *(const f32x4*)(v + D + kk*32 + g*8 + 4);
            #pragma unroll
            for(int q=0;q<4;++q){
                ds = fmaf(lo[q], vsl[q], ds); ds = fmaf(hi[q], vsh[q], ds);
                dd = fmaf(lo[q], vdl[q], dd); dd = fmaf(hi[q], vdh[q], dd);
            }
            short8 af = pack8m(lo, hi);
            #pragma unroll
            for(int j=0;j<8;++j){
                short8 wfj = *(const short8*)(&Wlds[(j*16+t)*136 + kk*32 + g*8]);
                acc[j] = __builtin_amdgcn_mfma_f32_16x16x32_bf16(af, wfj, acc[j], 0,0,0);
            }
        }
        ds += __shfl_xor(ds,16); ds += __shfl_xor(ds,32);
        dd += __shfl_xor(dd,16); dd += __shfl_xor(dd,32);
        if(g==0 && row0 < N){ ss[row0] = ds + c_s; sd[row0] = dd + c_d; }
        #pragma unroll
        for(int r=0;r<4;++r){
            int rr = rt*16 + g*4 + r;
            if(rr < N){
                short8 h;
                #pragma unroll
                for(int j=0;j<8;++j) h[j] = (short)f2bf(acc[j][r] + bb[j]);
                *(short8*)(Hp + (size_t)rr*D + t*8) = h;
            }
        }
    }
}

// P2a: block sums of 4096-chunks
__global__ __launch_bounds__(256) void k_scanA(const unsigned* __restrict__ M,
        unsigned* __restrict__ bsum, int n){
    __shared__ unsigned lds[4];
    int base = blockIdx.x*4096 + threadIdx.x*16;
    unsigned s=0;
    #pragma unroll
    for(int k=0;k<16;++k){ int i=base+k; if(i<n) s+=M[i]; }
    #pragma unroll
    for(int o=1;o<64;o<<=1) s += __shfl_xor(s,o);
    if((threadIdx.x&63)==0) lds[threadIdx.x>>6]=s;
    __syncthreads();
    if(threadIdx.x==0) bsum[blockIdx.x] = lds[0]+lds[1]+lds[2]+lds[3];
}

// P2b: per-block local exclusive scan; block prefix = reduce of raw bsum[0..b) (nsb<=128)
__global__ __launch_bounds__(256) void k_scanC(const unsigned* __restrict__ M,
        const unsigned* __restrict__ bsum, unsigned* __restrict__ Msc, int n, int nsb){
    __shared__ unsigned lds[4];
    __shared__ unsigned ps[2];
    int t = threadIdx.x;
    unsigned pv = (t < nsb && t < (int)blockIdx.x) ? bsum[t] : 0u;
    #pragma unroll
    for(int o=1;o<64;o<<=1) pv += __shfl_xor(pv,o);
    if((t&63)==0 && t<128) ps[t>>6]=pv;
    int base = blockIdx.x*4096 + t*16;
    unsigned v[16]; unsigned tsum=0;
    #pragma unroll
    for(int k=0;k<16;++k){ int i=base+k; v[k]=(i<n)?M[i]:0u; tsum+=v[k]; }
    unsigned x=tsum;
    #pragma unroll
    for(int o=1;o<64;o<<=1){ unsigned y=__shfl_up(x,(unsigned)o); if((t&63)>=o) x+=y; }
    if((t&63)==63) lds[t>>6]=x;
    __syncthreads();
    unsigned run = ps[0]+ps[1];
    for(int w=0;w<(t>>6);++w) run += lds[w];
    run += (x - tsum);
    #pragma unroll
    for(int k=0;k<16;++k){ int i=base+k; if(i<n) Msc[i]=run; run+=v[k]; }
}

// P3: bucket-partition edges; per-edge exp-weight computed here (streaming, high TLP).
__global__ __launch_bounds__(256) void k_bscatter(const int* __restrict__ src,
        const int* __restrict__ dst, const unsigned* __restrict__ Msc,
        const float* __restrict__ ss, const float* __restrict__ sdv,
        uint2* __restrict__ ew, int E, int NB, int CHUNK){
    __shared__ unsigned hoff[1600];
    int blk = blockIdx.x, NBLKg = gridDim.x;
    for(int i=threadIdx.x;i<NB;i+=256) hoff[i] = Msc[(size_t)i*NBLKg + blk];
    __syncthreads();
    int s0 = blk*CHUNK;
    int e1 = s0+CHUNK < E ? s0+CHUNK : E;
    for(int i=s0+(int)threadIdx.x;i<e1;i+=256){
        int d = dst[i];
        int s = src[i];
        float w = __expf(leaky(ss[s] + sdv[d]));
        unsigned p = atomicAdd(&hoff[((unsigned)d)>>6], 1u);
        ew[p] = make_uint2(((unsigned)s<<6)|((unsigned)d&63u), __float_as_uint(w));
    }
}

__device__ __forceinline__ void fma8(float* acc, uint4 u, float w){
    acc[0]=fmaf(w,__uint_as_float(u.x<<16),acc[0]);
    acc[1]=fmaf(w,__uint_as_float(u.x&0xffff0000u),acc[1]);
    acc[2]=fmaf(w,__uint_as_float(u.y<<16),acc[2]);
    acc[3]=fmaf(w,__uint_as_float(u.y&0xffff0000u),acc[3]);
    acc[4]=fmaf(w,__uint_as_float(u.z<<16),acc[4]);
    acc[5]=fmaf(w,__uint_as_float(u.z&0xffff0000u),acc[5]);
    acc[6]=fmaf(w,__uint_as_float(u.w<<16),acc[6]);
    acc[7]=fmaf(w,__uint_as_float(u.w&0xffff0000u),acc[7]);
}

// Fused fine-sort + gather: block = one 64-dst bucket. Counting-sort the bucket's
// (src,w) descriptors into LDS, then per-dst weighted gather (4 edges/iter,
// 16 lanes/edge) reading descriptors from LDS. Rare oversized buckets fall back
// to a correct scan-from-global path.
__global__ __launch_bounds__(256) void k_gfine(const uint2* __restrict__ ew,
        const unsigned* __restrict__ Msc, const unsigned short* __restrict__ Hp,
        float* __restrict__ out, int N, int NB, int E){
    __shared__ uint2 sed[CAP+16];
    __shared__ unsigned cA[64], cB[64], loff[64];
    __shared__ unsigned begS, endS;
    const int b = blockIdx.x;
    const int dbase = b<<6;
    const int tid = threadIdx.x;
    if(tid==0){
        begS = Msc[(size_t)b*256];
        endS = (b+1 < NB) ? Msc[(size_t)(b+1)*256] : (unsigned)E;
    }
    if(tid<64){ cA[tid]=0u; cB[tid]=0u; }
    __syncthreads();
    const unsigned beg = begS;
    const unsigned size = endS - begS;
    const int wv = tid>>6, l = tid&63;
    const int g = l>>4, t = l&15;
    const unsigned toff = (unsigned)t*16u;

    if(size <= CAP){
        for(unsigned i=tid; i<size; i+=256)
            atomicAdd(&cA[ew[beg+i].x & 63u], 1u);
        __syncthreads();
        if(tid<64){
            unsigned c = cA[tid];
            unsigned x = c;
            #pragma unroll
            for(int o=1;o<64;o<<=1){ unsigned y = __shfl_up(x,(unsigned)o); if(tid>=o) x += y; }
            loff[tid] = x - c;
        }
        __syncthreads();
        for(unsigned i=tid; i<size; i+=256){
            uint2 p = ew[beg+i];
            unsigned dl = p.x & 63u;
            unsigned r = atomicAdd(&cB[dl], 1u);
            sed[loff[dl]+r] = make_uint2(p.x>>6, p.y);
        }
        for(unsigned i=size+tid; i<size+16u; i+=256) sed[i] = make_uint2(0u,0u);
        __syncthreads();
        #pragma unroll 1
        for(int i=0;i<16;++i){
            int dl = i*4 + wv;
            int d = dbase + dl;
            if(d >= N) continue;                      // wave-uniform
            unsigned kb = loff[dl], ke = kb + cB[dl];
            float acc[8];
            #pragma unroll
            for(int j=0;j<8;++j) acc[j]=0.f;
            float den = 0.f;
            unsigned e = kb + g;
            uint2 p0 = sed[e];
            uint4 u0 = *(const uint4*)((const char*)Hp + ((p0.x<<8) + toff));
            uint2 p1 = sed[e+4];
            uint4 u1 = *(const uint4*)((const char*)Hp + ((p1.x<<8) + toff));
            while(e < ke){
                float w0 = __uint_as_float(p0.y);
                fma8(acc, u0, w0);
                p0 = sed[e+8];
                u0 = *(const uint4*)((const char*)Hp + ((p0.x<<8) + toff));
                float w1 = (e+4 < ke) ? __uint_as_float(p1.y) : 0.f;
                fma8(acc, u1, w1);
                p1 = sed[e+12];
                u1 = *(const uint4*)((const char*)Hp + ((p1.x<<8) + toff));
                den += w0 + w1;
                e += 8;
            }
            #pragma unroll
            for(int j=0;j<8;++j){
                acc[j] += __shfl_xor(acc[j],16);
                acc[j] += __shfl_xor(acc[j],32);
            }
            den += __shfl_xor(den,16);
            den += __shfl_xor(den,32);
            float inv = 1.f/(den + 1e-9f);
            int c = g*32 + t;
            out[(size_t)d*D + c]      = acc[g*2]  * inv;
            out[(size_t)d*D + c + 16] = acc[g*2+1]* inv;
        }
    } else {
        // fallback (statistically never for uniform dst): scan whole bucket per dst
        #pragma unroll 1
        for(int i=0;i<16;++i){
            int dl = i*4 + wv;
            int d = dbase + dl;
            if(d >= N) continue;
            float acc[8];
            #pragma unroll
            for(int j=0;j<8;++j) acc[j]=0.f;
            float den = 0.f;
            for(unsigned e2 = beg + (unsigned)g; e2 < beg + size; e2 += 4){
                uint2 p = ew[e2];
                if((int)(p.x & 63u) != dl) continue;
                float w = __uint_as_float(p.y);
                uint4 u = *(const uint4*)((const char*)Hp + (((p.x>>6)<<8) + toff));
                fma8(acc, u, w);
                den += w;
            }
            #pragma unroll
            for(int j=0;j<8;++j){
                acc[j] += __shfl_xor(acc[j],16);
                acc[j] += __shfl_xor(acc[j],32);
            }
            den += __shfl_xor(den,16);
            den += __shfl_xor(den,32);
            float inv = 1.f/(den + 1e-9f);
            int c = g*32 + t;
            out[(size_t)d*D + c]      = acc[g*2]  * inv;
            out[(size_t)d*D + c + 16] = acc[g*2+1]* inv;
        }
    }
}

// out = leaky(f + h + (f*h)@W2^T + b2), in place on out; W2 (bf16) staged in LDS
__global__ __launch_bounds__(256) void k_final(const float* __restrict__ F,
        const unsigned short* __restrict__ W2b, const float* __restrict__ b2,
        float* __restrict__ out, int N, int GF){
    __shared__ __align__(16) unsigned short Wlds[17408];
    #pragma unroll
    for(int k=0;k<8;++k){
        int idx = ((int)threadIdx.x + k*256)*8;
        int row = idx >> 7, col = idx & 127;
        *(short8*)(&Wlds[row*136 + col]) = *(const short8*)(W2b + idx);
    }
    __syncthreads();
    const int lane = threadIdx.x & 63, wv = threadIdx.x>>6;
    const int t = lane & 15, g = lane >> 4;
    float bb[8];
    #pragma unroll
    for(int j=0;j<8;++j) bb[j] = b2[j*16+t];
    const int Mt = (N+15)>>4;
    for(int rt = (int)blockIdx.x*4 + wv; rt < Mt; rt += GF*4){
        int row = rt*16 + t; if(row>=N) row = N-1;
        const float* fr = F   + (size_t)row*D + g*8;
        const float* hr = out + (size_t)row*D + g*8;
        f32x4 acc[8];
        #pragma unroll
        for(int j=0;j<8;++j) acc[j] = (f32x4){0.f,0.f,0.f,0.f};
        #pragma unroll
        for(int kk=0;kk<4;++kk){
            f32x4 flo = *(const f32x4*)(fr + kk*32);
            f32x4 fhi = *(const f32x4*)(fr + kk*32 + 4);
            f32x4 hlo = *(const f32x4*)(hr + kk*32);
            f32x4 hhi = *(const f32x4*)(hr + kk*32 + 4);
            short8 af = pack8m(flo*hlo, fhi*hhi);
            #pragma unroll
            for(int j=0;j<8;++j){
                short8 wfj = *(const short8*)(&Wlds[(j*16+t)*136 + kk*32 + g*8]);
                acc[j] = __builtin_amdgcn_mfma_f32_16x16x32_bf16(af, wfj, acc[j], 0,0,0);
            }
        }
        #pragma unroll
        for(int r=0;r<4;++r){
            int rr = rt*16 + g*4 + r;
            if(rr < N){
                #pragma unroll
                for(int j=0;j<8;++j){
                    int c = j*16 + t;
                    float f = F[(size_t)rr*D + c];
                    float h = out[(size_t)rr*D + c];
                    out[(size_t)rr*D + c] = leaky(f + h + acc[j][r] + bb[j]);
                }
            }
        }
    }
}

extern "C" void kernel_launch(void* const* d_in, const int* in_sizes, int n_in,
                              void* d_out, int out_size, void* d_ws, size_t ws_size,
                              hipStream_t stream) {
    const int*   idx  = (const int*)  d_in[0];   // (2,E)
    const float* F    = (const float*)d_in[1];   // (N,128)
    const float* Waw  = (const float*)d_in[3];
    const float* Wab  = (const float*)d_in[4];
    const float* W1w  = (const float*)d_in[5];
    const float* W1b  = (const float*)d_in[6];
    const float* W2w  = (const float*)d_in[7];
    const float* W2b  = (const float*)d_in[8];
    const float* a    = (const float*)d_in[9];
    float* out = (float*)d_out;

    const int E = in_sizes[0]/2;
    const int N = in_sizes[1]/D;
    const int* srcp = idx;
    const int* dstp = idx + E;

    const int NBLK = 256;
    const int CHUNK = (E + NBLK - 1)/NBLK;
    const int NB = (N + 63)/64;            // coarse buckets (<=1600)
    const int NT = NB*NBLK;
    const int NSB = (NT + 4095)/4096;      // <=128 by construction

    uint2*    ew   = (uint2*)d_ws;                          // E
    unsigned short* Hp  = (unsigned short*)(ew + E);        // N*128 bf16
    unsigned short* W1c = Hp + (size_t)N*D;                 // 16384
    unsigned short* W2c = W1c + 16384;                      // 16384
    float*    ss   = (float*)(W2c + 16384);                 // N
    float*    sd   = ss + N;                                // N
    float*    v    = sd + N;                                // 320
    unsigned* M    = (unsigned*)(v + 320);                  // NT
    unsigned* Msc  = M + NT;                                // NT+2
    unsigned* bsum = Msc + NT + 2;                          // NSB

    const int Mt = (N+15)/16;
    const int GT = (Mt+3)/4;               // 1 tile per wave
    const int GF = GT;

    k_prep    <<<65, 256, 0, stream>>>(Waw, Wab, a, v, W1w, W2w, W1c, W2c);
    k_msgscal <<<GT+NBLK, 256, 0, stream>>>(F, W1c, W1b, v, Hp, ss, sd, N,
                                            dstp, M, E, GT, CHUNK, NB);
    k_scanA   <<<NSB, 256, 0, stream>>>(M, bsum, NT);
    k_scanC   <<<NSB, 256, 0, stream>>>(M, bsum, Msc, NT, NSB);
    k_bscatter<<<NBLK, 256, 0, stream>>>(srcp, dstp, Msc, ss, sd, ew, E, NB, CHUNK);
    k_gfine   <<<NB, 256, 0, stream>>>(ew, Msc, Hp, out, N, NB, E);
    k_final   <<<GF, 256, 0, stream>>>(F, W2c, W2b, out, N, GF);
}

// Round 16
// 181.805 us; speedup vs baseline: 1.4012x; 1.0213x over previous
//
#include <hip/hip_runtime.h>

#define D 128
#define CAP 2560
typedef __attribute__((ext_vector_type(8))) short short8;
typedef __attribute__((ext_vector_type(4))) float f32x4;

__device__ __forceinline__ float leaky(float x){ return x >= 0.f ? x : 0.01f*x; }
__device__ __forceinline__ unsigned short f2bf(float x){
    unsigned u = __float_as_uint(x);
    u = (u + 0x7fffu + ((u>>16)&1u)) >> 16;
    return (unsigned short)u;
}
__device__ __forceinline__ short8 pack8m(f32x4 a, f32x4 b){
    short8 s;
    s[0]=(short)f2bf(a[0]); s[1]=(short)f2bf(a[1]);
    s[2]=(short)f2bf(a[2]); s[3]=(short)f2bf(a[3]);
    s[4]=(short)f2bf(b[0]); s[5]=(short)f2bf(b[1]);
    s[6]=(short)f2bf(b[2]); s[7]=(short)f2bf(b[3]);
    return s;
}

// fold attention vectors + convert W1/W2 to bf16 + zero bsum
__global__ void k_prep(const float* __restrict__ Ww, const float* __restrict__ Wb,
                       const float* __restrict__ a, float* __restrict__ v,
                       const float* __restrict__ W1, const float* __restrict__ W2,
                       unsigned short* __restrict__ W1b, unsigned short* __restrict__ W2b,
                       unsigned* __restrict__ bsum, int NSB){
    int b = blockIdx.x;
    if(b < 64){
        int i = b*256 + threadIdx.x; // 0..16383
        W1b[i] = f2bf(W1[i]);
        W2b[i] = f2bf(W2[i]);
        return;
    }
    if(b == 65){
        if((int)threadIdx.x < NSB) bsum[threadIdx.x] = 0u;
        return;
    }
    int i = threadIdx.x; if(i >= 128) return;
    float vs=0.f, vd=0.f;
    for (int o=0;o<D;++o){ float w = Ww[o*D+i]; vs = fmaf(w, a[o], vs); vd = fmaf(w, a[D+o], vd); }
    v[i]=vs; v[D+i]=vd;
    if(i==0){
        float cs=0.f,cd=0.f;
        for(int o=0;o<D;++o){ cs=fmaf(Wb[o],a[o],cs); cd=fmaf(Wb[o],a[D+o],cd); }
        v[256]=cs; v[257]=cd;
    }
}

// Fused: [blocks < GT]  H_perm = bf16(F @ W1^T + b1) + attention scalars ss/sd
//        (weights in LDS, ~3 tiles/wave).
//        [blocks >= GT] coarse bucket histogram + superblock sums into bsum.
__global__ __launch_bounds__(256) void k_msgscal(const float* __restrict__ F,
        const unsigned short* __restrict__ W1b, const float* __restrict__ b1,
        const float* __restrict__ v, unsigned short* __restrict__ Hp,
        float* __restrict__ ss, float* __restrict__ sd, int N,
        const int* __restrict__ dst, unsigned* __restrict__ M,
        unsigned* __restrict__ bsum, int E, int GT, int CHUNK, int NB, int NSB){
    __shared__ __align__(16) unsigned short Wlds[17408];   // 128 rows x 136 halfwords
    if((int)blockIdx.x >= GT){
        unsigned* h = (unsigned*)Wlds;                      // 1600 x 4B overlay
        for(int i=threadIdx.x;i<1600;i+=256) h[i]=0u;
        __syncthreads();
        int blk = (int)blockIdx.x - GT;
        int s = blk*CHUNK;
        int e = s+CHUNK < E ? s+CHUNK : E;
        for(int i=s+(int)threadIdx.x;i<e;i+=256) atomicAdd(&h[((unsigned)dst[i])>>6],1u);
        __syncthreads();
        for(int j=threadIdx.x;j<NB;j+=256) M[(size_t)j*256 + blk] = h[j];
        for(int sb=threadIdx.x; sb<NSB; sb+=256){
            unsigned sum=0;
            for(int k=0;k<16;++k) sum += h[sb*16+k];
            atomicAdd(&bsum[sb], sum);
        }
        return;
    }
    #pragma unroll
    for(int k=0;k<8;++k){
        int idx = ((int)threadIdx.x + k*256)*8;
        int row = idx >> 7, col = idx & 127;
        *(short8*)(&Wlds[row*136 + col]) = *(const short8*)(W1b + idx);
    }
    __syncthreads();
    const int lane = threadIdx.x & 63, wv = threadIdx.x>>6;
    const int t = lane & 15, g = lane >> 4;
    float bb[8];
    #pragma unroll
    for(int j=0;j<8;++j) bb[j] = b1[j*16+t];
    const float c_s = v[256], c_d = v[257];
    const int Mt = (N+15)>>4;
    for(int rt = (int)blockIdx.x*4 + wv; rt < Mt; rt += GT*4){
        int row0 = rt*16 + t;
        int row = row0 < N ? row0 : N-1;
        const float* fr = F + (size_t)row*D + g*8;
        f32x4 acc[8];
        #pragma unroll
        for(int j=0;j<8;++j) acc[j] = (f32x4){0.f,0.f,0.f,0.f};
        float ds = 0.f, dd = 0.f;
        #pragma unroll
        for(int kk=0;kk<4;++kk){
            f32x4 lo = *(const f32x4*)(fr + kk*32);
            f32x4 hi = *(const f32x4*)(fr + kk*32 + 4);
            f32x4 vsl = *(const f32x4*)(v + kk*32 + g*8);
            f32x4 vsh = *(const f32x4*)(v + kk*32 + g*8 + 4);
            f32x4 vdl = *(const f32x4*)(v + D + kk*32 + g*8);
            f32x4 vdh = *(const f32x4*)(v + D + kk*32 + g*8 + 4);
            #pragma unroll
            for(int q=0;q<4;++q){
                ds = fmaf(lo[q], vsl[q], ds); ds = fmaf(hi[q], vsh[q], ds);
                dd = fmaf(lo[q], vdl[q], dd); dd = fmaf(hi[q], vdh[q], dd);
            }
            short8 af = pack8m(lo, hi);
            #pragma unroll
            for(int j=0;j<8;++j){
                short8 wfj = *(const short8*)(&Wlds[(j*16+t)*136 + kk*32 + g*8]);
                acc[j] = __builtin_amdgcn_mfma_f32_16x16x32_bf16(af, wfj, acc[j], 0,0,0);
            }
        }
        ds += __shfl_xor(ds,16); ds += __shfl_xor(ds,32);
        dd += __shfl_xor(dd,16); dd += __shfl_xor(dd,32);
        if(g==0 && row0 < N){ ss[row0] = ds + c_s; sd[row0] = dd + c_d; }
        #pragma unroll
        for(int r=0;r<4;++r){
            int rr = rt*16 + g*4 + r;
            if(rr < N){
                short8 h;
                #pragma unroll
                for(int j=0;j<8;++j) h[j] = (short)f2bf(acc[j][r] + bb[j]);
                *(short8*)(Hp + (size_t)rr*D + t*8) = h;
            }
        }
    }
}

// P2: per-block local exclusive scan; block prefix = reduce of raw bsum[0..b) (nsb<=128)
__global__ __launch_bounds__(256) void k_scanC(const unsigned* __restrict__ M,
        const unsigned* __restrict__ bsum, unsigned* __restrict__ Msc, int n, int nsb){
    __shared__ unsigned lds[4];
    __shared__ unsigned ps[2];
    int t = threadIdx.x;
    unsigned pv = (t < nsb && t < (int)blockIdx.x) ? bsum[t] : 0u;
    #pragma unroll
    for(int o=1;o<64;o<<=1) pv += __shfl_xor(pv,o);
    if((t&63)==0 && t<128) ps[t>>6]=pv;
    int base = blockIdx.x*4096 + t*16;
    unsigned v[16]; unsigned tsum=0;
    #pragma unroll
    for(int k=0;k<16;++k){ int i=base+k; v[k]=(i<n)?M[i]:0u; tsum+=v[k]; }
    unsigned x=tsum;
    #pragma unroll
    for(int o=1;o<64;o<<=1){ unsigned y=__shfl_up(x,(unsigned)o); if((t&63)>=o) x+=y; }
    if((t&63)==63) lds[t>>6]=x;
    __syncthreads();
    unsigned run = ps[0]+ps[1];
    for(int w=0;w<(t>>6);++w) run += lds[w];
    run += (x - tsum);
    #pragma unroll
    for(int k=0;k<16;++k){ int i=base+k; if(i<n) Msc[i]=run; run+=v[k]; }
}

// P3: bucket-partition edges; per-edge exp-weight computed here (streaming, high TLP).
__global__ __launch_bounds__(256) void k_bscatter(const int* __restrict__ src,
        const int* __restrict__ dst, const unsigned* __restrict__ Msc,
        const float* __restrict__ ss, const float* __restrict__ sdv,
        uint2* __restrict__ ew, int E, int NB, int CHUNK){
    __shared__ unsigned hoff[1600];
    int blk = blockIdx.x, NBLKg = gridDim.x;
    for(int i=threadIdx.x;i<NB;i+=256) hoff[i] = Msc[(size_t)i*NBLKg + blk];
    __syncthreads();
    int s0 = blk*CHUNK;
    int e1 = s0+CHUNK < E ? s0+CHUNK : E;
    for(int i=s0+(int)threadIdx.x;i<e1;i+=256){
        int d = dst[i];
        int s = src[i];
        float w = __expf(leaky(ss[s] + sdv[d]));
        unsigned p = atomicAdd(&hoff[((unsigned)d)>>6], 1u);
        ew[p] = make_uint2(((unsigned)s<<6)|((unsigned)d&63u), __float_as_uint(w));
    }
}

__device__ __forceinline__ void fma8(float* acc, uint4 u, float w){
    acc[0]=fmaf(w,__uint_as_float(u.x<<16),acc[0]);
    acc[1]=fmaf(w,__uint_as_float(u.x&0xffff0000u),acc[1]);
    acc[2]=fmaf(w,__uint_as_float(u.y<<16),acc[2]);
    acc[3]=fmaf(w,__uint_as_float(u.y&0xffff0000u),acc[3]);
    acc[4]=fmaf(w,__uint_as_float(u.z<<16),acc[4]);
    acc[5]=fmaf(w,__uint_as_float(u.z&0xffff0000u),acc[5]);
    acc[6]=fmaf(w,__uint_as_float(u.w<<16),acc[6]);
    acc[7]=fmaf(w,__uint_as_float(u.w&0xffff0000u),acc[7]);
}

// Fused fine-sort + gather: block = one 64-dst bucket. Counting-sort into LDS,
// then per-dst weighted gather (4 edges/iter, 16 lanes/edge).
__global__ __launch_bounds__(256) void k_gfine(const uint2* __restrict__ ew,
        const unsigned* __restrict__ Msc, const unsigned short* __restrict__ Hp,
        float* __restrict__ out, int N, int NB, int E){
    __shared__ uint2 sed[CAP+16];
    __shared__ unsigned cA[64], cB[64], loff[64];
    __shared__ unsigned begS, endS;
    const int b = blockIdx.x;
    const int dbase = b<<6;
    const int tid = threadIdx.x;
    if(tid==0){
        begS = Msc[(size_t)b*256];
        endS = (b+1 < NB) ? Msc[(size_t)(b+1)*256] : (unsigned)E;
    }
    if(tid<64){ cA[tid]=0u; cB[tid]=0u; }
    __syncthreads();
    const unsigned beg = begS;
    const unsigned size = endS - begS;
    const int wv = tid>>6, l = tid&63;
    const int g = l>>4, t = l&15;
    const unsigned toff = (unsigned)t*16u;

    if(size <= CAP){
        for(unsigned i=tid; i<size; i+=256)
            atomicAdd(&cA[ew[beg+i].x & 63u], 1u);
        __syncthreads();
        if(tid<64){
            unsigned c = cA[tid];
            unsigned x = c;
            #pragma unroll
            for(int o=1;o<64;o<<=1){ unsigned y = __shfl_up(x,(unsigned)o); if(tid>=o) x += y; }
            loff[tid] = x - c;
        }
        __syncthreads();
        for(unsigned i=tid; i<size; i+=256){
            uint2 p = ew[beg+i];
            unsigned dl = p.x & 63u;
            unsigned r = atomicAdd(&cB[dl], 1u);
            sed[loff[dl]+r] = make_uint2(p.x>>6, p.y);
        }
        for(unsigned i=size+tid; i<size+16u; i+=256) sed[i] = make_uint2(0u,0u);
        __syncthreads();
        #pragma unroll 1
        for(int i=0;i<16;++i){
            int dl = i*4 + wv;
            int d = dbase + dl;
            if(d >= N) continue;                      // wave-uniform
            unsigned kb = loff[dl], ke = kb + cB[dl];
            float acc[8];
            #pragma unroll
            for(int j=0;j<8;++j) acc[j]=0.f;
            float den = 0.f;
            unsigned e = kb + g;
            uint2 p0 = sed[e];
            uint4 u0 = *(const uint4*)((const char*)Hp + ((p0.x<<8) + toff));
            uint2 p1 = sed[e+4];
            uint4 u1 = *(const uint4*)((const char*)Hp + ((p1.x<<8) + toff));
            while(e < ke){
                float w0 = __uint_as_float(p0.y);
                fma8(acc, u0, w0);
                p0 = sed[e+8];
                u0 = *(const uint4*)((const char*)Hp + ((p0.x<<8) + toff));
                float w1 = (e+4 < ke) ? __uint_as_float(p1.y) : 0.f;
                fma8(acc, u1, w1);
                p1 = sed[e+12];
                u1 = *(const uint4*)((const char*)Hp + ((p1.x<<8) + toff));
                den += w0 + w1;
                e += 8;
            }
            #pragma unroll
            for(int j=0;j<8;++j){
                acc[j] += __shfl_xor(acc[j],16);
                acc[j] += __shfl_xor(acc[j],32);
            }
            den += __shfl_xor(den,16);
            den += __shfl_xor(den,32);
            float inv = 1.f/(den + 1e-9f);
            int c = g*32 + t;
            out[(size_t)d*D + c]      = acc[g*2]  * inv;
            out[(size_t)d*D + c + 16] = acc[g*2+1]* inv;
        }
    } else {
        #pragma unroll 1
        for(int i=0;i<16;++i){
            int dl = i*4 + wv;
            int d = dbase + dl;
            if(d >= N) continue;
            float acc[8];
            #pragma unroll
            for(int j=0;j<8;++j) acc[j]=0.f;
            float den = 0.f;
            for(unsigned e2 = beg + (unsigned)g; e2 < beg + size; e2 += 4){
                uint2 p = ew[e2];
                if((int)(p.x & 63u) != dl) continue;
                float w = __uint_as_float(p.y);
                uint4 u = *(const uint4*)((const char*)Hp + (((p.x>>6)<<8) + toff));
                fma8(acc, u, w);
                den += w;
            }
            #pragma unroll
            for(int j=0;j<8;++j){
                acc[j] += __shfl_xor(acc[j],16);
                acc[j] += __shfl_xor(acc[j],32);
            }
            den += __shfl_xor(den,16);
            den += __shfl_xor(den,32);
            float inv = 1.f/(den + 1e-9f);
            int c = g*32 + t;
            out[(size_t)d*D + c]      = acc[g*2]  * inv;
            out[(size_t)d*D + c + 16] = acc[g*2+1]* inv;
        }
    }
}

// out = leaky(f + h + (f*h)@W2^T + b2), in place on out; W2 (bf16) staged in LDS
__global__ __launch_bounds__(256) void k_final(const float* __restrict__ F,
        const unsigned short* __restrict__ W2b, const float* __restrict__ b2,
        float* __restrict__ out, int N, int GF){
    __shared__ __align__(16) unsigned short Wlds[17408];
    #pragma unroll
    for(int k=0;k<8;++k){
        int idx = ((int)threadIdx.x + k*256)*8;
        int row = idx >> 7, col = idx & 127;
        *(short8*)(&Wlds[row*136 + col]) = *(const short8*)(W2b + idx);
    }
    __syncthreads();
    const int lane = threadIdx.x & 63, wv = threadIdx.x>>6;
    const int t = lane & 15, g = lane >> 4;
    float bb[8];
    #pragma unroll
    for(int j=0;j<8;++j) bb[j] = b2[j*16+t];
    const int Mt = (N+15)>>4;
    for(int rt = (int)blockIdx.x*4 + wv; rt < Mt; rt += GF*4){
        int row = rt*16 + t; if(row>=N) row = N-1;
        const float* fr = F   + (size_t)row*D + g*8;
        const float* hr = out + (size_t)row*D + g*8;
        f32x4 acc[8];
        #pragma unroll
        for(int j=0;j<8;++j) acc[j] = (f32x4){0.f,0.f,0.f,0.f};
        #pragma unroll
        for(int kk=0;kk<4;++kk){
            f32x4 flo = *(const f32x4*)(fr + kk*32);
            f32x4 fhi = *(const f32x4*)(fr + kk*32 + 4);
            f32x4 hlo = *(const f32x4*)(hr + kk*32);
            f32x4 hhi = *(const f32x4*)(hr + kk*32 + 4);
            short8 af = pack8m(flo*hlo, fhi*hhi);
            #pragma unroll
            for(int j=0;j<8;++j){
                short8 wfj = *(const short8*)(&Wlds[(j*16+t)*136 + kk*32 + g*8]);
                acc[j] = __builtin_amdgcn_mfma_f32_16x16x32_bf16(af, wfj, acc[j], 0,0,0);
            }
        }
        #pragma unroll
        for(int r=0;r<4;++r){
            int rr = rt*16 + g*4 + r;
            if(rr < N){
                #pragma unroll
                for(int j=0;j<8;++j){
                    int c = j*16 + t;
                    float f = F[(size_t)rr*D + c];
                    float h = out[(size_t)rr*D + c];
                    out[(size_t)rr*D + c] = leaky(f + h + acc[j][r] + bb[j]);
                }
            }
        }
    }
}

extern "C" void kernel_launch(void* const* d_in, const int* in_sizes, int n_in,
                              void* d_out, int out_size, void* d_ws, size_t ws_size,
                              hipStream_t stream) {
    const int*   idx  = (const int*)  d_in[0];   // (2,E)
    const float* F    = (const float*)d_in[1];   // (N,128)
    const float* Waw  = (const float*)d_in[3];
    const float* Wab  = (const float*)d_in[4];
    const float* W1w  = (const float*)d_in[5];
    const float* W1b  = (const float*)d_in[6];
    const float* W2w  = (const float*)d_in[7];
    const float* W2b  = (const float*)d_in[8];
    const float* a    = (const float*)d_in[9];
    float* out = (float*)d_out;

    const int E = in_sizes[0]/2;
    const int N = in_sizes[1]/D;
    const int* srcp = idx;
    const int* dstp = idx + E;

    const int NBLK = 256;
    const int CHUNK = (E + NBLK - 1)/NBLK;
    const int NB = (N + 63)/64;            // coarse buckets (<=1600)
    const int NT = NB*NBLK;
    const int NSB = (NT + 4095)/4096;      // <=100 by construction

    uint2*    ew   = (uint2*)d_ws;                          // E
    unsigned short* Hp  = (unsigned short*)(ew + E);        // N*128 bf16
    unsigned short* W1c = Hp + (size_t)N*D;                 // 16384
    unsigned short* W2c = W1c + 16384;                      // 16384
    float*    ss   = (float*)(W2c + 16384);                 // N
    float*    sd   = ss + N;                                // N
    float*    v    = sd + N;                                // 320
    unsigned* M    = (unsigned*)(v + 320);                  // NT
    unsigned* Msc  = M + NT;                                // NT+2
    unsigned* bsum = Msc + NT + 2;                          // NSB

    const int GT = 512;
    const int GF = 512;

    k_prep    <<<66, 256, 0, stream>>>(Waw, Wab, a, v, W1w, W2w, W1c, W2c, bsum, NSB);
    k_msgscal <<<GT+NBLK, 256, 0, stream>>>(F, W1c, W1b, v, Hp, ss, sd, N,
                                            dstp, M, bsum, E, GT, CHUNK, NB, NSB);
    k_scanC   <<<NSB, 256, 0, stream>>>(M, bsum, Msc, NT, NSB);
    k_bscatter<<<NBLK, 256, 0, stream>>>(srcp, dstp, Msc, ss, sd, ew, E, NB, CHUNK);
    k_gfine   <<<NB, 256, 0, stream>>>(ew, Msc, Hp, out, N, NB, E);
    k_final   <<<GF, 256, 0, stream>>>(F, W2c, W2b, out, N, GF);
}

// Round 17
// 179.018 us; speedup vs baseline: 1.4230x; 1.0156x over previous
//
#include <hip/hip_runtime.h>

#define D 128
#define CAP 2560
typedef __attribute__((ext_vector_type(8))) short short8;
typedef __attribute__((ext_vector_type(4))) float f32x4;

__device__ __forceinline__ float leaky(float x){ return x >= 0.f ? x : 0.01f*x; }
__device__ __forceinline__ unsigned short f2bf(float x){
    unsigned u = __float_as_uint(x);
    u = (u + 0x7fffu + ((u>>16)&1u)) >> 16;
    return (unsigned short)u;
}
__device__ __forceinline__ short8 pack8m(f32x4 a, f32x4 b){
    short8 s;
    s[0]=(short)f2bf(a[0]); s[1]=(short)f2bf(a[1]);
    s[2]=(short)f2bf(a[2]); s[3]=(short)f2bf(a[3]);
    s[4]=(short)f2bf(b[0]); s[5]=(short)f2bf(b[1]);
    s[6]=(short)f2bf(b[2]); s[7]=(short)f2bf(b[3]);
    return s;
}

// fold attention vectors + convert W1/W2 to bf16 + zero bsum
__global__ void k_prep(const float* __restrict__ Ww, const float* __restrict__ Wb,
                       const float* __restrict__ a, float* __restrict__ v,
                       const float* __restrict__ W1, const float* __restrict__ W2,
                       unsigned short* __restrict__ W1b, unsigned short* __restrict__ W2b,
                       unsigned* __restrict__ bsum, int NSB){
    int b = blockIdx.x;
    if(b < 64){
        int i = b*256 + threadIdx.x; // 0..16383
        W1b[i] = f2bf(W1[i]);
        W2b[i] = f2bf(W2[i]);
        return;
    }
    if(b == 65){
        if((int)threadIdx.x < NSB) bsum[threadIdx.x] = 0u;
        return;
    }
    int i = threadIdx.x; if(i >= 128) return;
    float vs=0.f, vd=0.f;
    for (int o=0;o<D;++o){ float w = Ww[o*D+i]; vs = fmaf(w, a[o], vs); vd = fmaf(w, a[D+o], vd); }
    v[i]=vs; v[D+i]=vd;
    if(i==0){
        float cs=0.f,cd=0.f;
        for(int o=0;o<D;++o){ cs=fmaf(Wb[o],a[o],cs); cd=fmaf(Wb[o],a[D+o],cd); }
        v[256]=cs; v[257]=cd;
    }
}

// Fused: [blocks < GT]  H_perm = bf16(F @ W1^T + b1) + attention scalars ss/sd
//        (weights in LDS, ~3 tiles/wave).
//        [blocks >= GT] coarse bucket histogram + superblock sums into bsum.
__global__ __launch_bounds__(256) void k_msgscal(const float* __restrict__ F,
        const unsigned short* __restrict__ W1b, const float* __restrict__ b1,
        const float* __restrict__ v, unsigned short* __restrict__ Hp,
        float* __restrict__ ss, float* __restrict__ sd, int N,
        const int* __restrict__ dst, unsigned* __restrict__ M,
        unsigned* __restrict__ bsum, int E, int GT, int CHUNK, int NB, int NSB){
    __shared__ __align__(16) unsigned short Wlds[17408];   // 128 rows x 136 halfwords
    if((int)blockIdx.x >= GT){
        unsigned* h = (unsigned*)Wlds;                      // 1600 x 4B overlay
        for(int i=threadIdx.x;i<1600;i+=256) h[i]=0u;
        __syncthreads();
        int blk = (int)blockIdx.x - GT;
        int s = blk*CHUNK;
        int e = s+CHUNK < E ? s+CHUNK : E;
        for(int i=s+(int)threadIdx.x;i<e;i+=256) atomicAdd(&h[((unsigned)dst[i])>>6],1u);
        __syncthreads();
        for(int j=threadIdx.x;j<NB;j+=256) M[(size_t)j*256 + blk] = h[j];
        for(int sb=threadIdx.x; sb<NSB; sb+=256){
            unsigned sum=0;
            for(int k=0;k<16;++k) sum += h[sb*16+k];
            atomicAdd(&bsum[sb], sum);
        }
        return;
    }
    #pragma unroll
    for(int k=0;k<8;++k){
        int idx = ((int)threadIdx.x + k*256)*8;
        int row = idx >> 7, col = idx & 127;
        *(short8*)(&Wlds[row*136 + col]) = *(const short8*)(W1b + idx);
    }
    __syncthreads();
    const int lane = threadIdx.x & 63, wv = threadIdx.x>>6;
    const int t = lane & 15, g = lane >> 4;
    float bb[8];
    #pragma unroll
    for(int j=0;j<8;++j) bb[j] = b1[j*16+t];
    const float c_s = v[256], c_d = v[257];
    const int Mt = (N+15)>>4;
    for(int rt = (int)blockIdx.x*4 + wv; rt < Mt; rt += GT*4){
        int row0 = rt*16 + t;
        int row = row0 < N ? row0 : N-1;
        const float* fr = F + (size_t)row*D + g*8;
        f32x4 acc[8];
        #pragma unroll
        for(int j=0;j<8;++j) acc[j] = (f32x4){0.f,0.f,0.f,0.f};
        float ds = 0.f, dd = 0.f;
        #pragma unroll
        for(int kk=0;kk<4;++kk){
            f32x4 lo = *(const f32x4*)(fr + kk*32);
            f32x4 hi = *(const f32x4*)(fr + kk*32 + 4);
            f32x4 vsl = *(const f32x4*)(v + kk*32 + g*8);
            f32x4 vsh = *(const f32x4*)(v + kk*32 + g*8 + 4);
            f32x4 vdl = *(const f32x4*)(v + D + kk*32 + g*8);
            f32x4 vdh = *(const f32x4*)(v + D + kk*32 + g*8 + 4);
            #pragma unroll
            for(int q=0;q<4;++q){
                ds = fmaf(lo[q], vsl[q], ds); ds = fmaf(hi[q], vsh[q], ds);
                dd = fmaf(lo[q], vdl[q], dd); dd = fmaf(hi[q], vdh[q], dd);
            }
            short8 af = pack8m(lo, hi);
            #pragma unroll
            for(int j=0;j<8;++j){
                short8 wfj = *(const short8*)(&Wlds[(j*16+t)*136 + kk*32 + g*8]);
                acc[j] = __builtin_amdgcn_mfma_f32_16x16x32_bf16(af, wfj, acc[j], 0,0,0);
            }
        }
        ds += __shfl_xor(ds,16); ds += __shfl_xor(ds,32);
        dd += __shfl_xor(dd,16); dd += __shfl_xor(dd,32);
        if(g==0 && row0 < N){ ss[row0] = ds + c_s; sd[row0] = dd + c_d; }
        #pragma unroll
        for(int r=0;r<4;++r){
            int rr = rt*16 + g*4 + r;
            if(rr < N){
                short8 h;
                #pragma unroll
                for(int j=0;j<8;++j) h[j] = (short)f2bf(acc[j][r] + bb[j]);
                *(short8*)(Hp + (size_t)rr*D + t*8) = h;
            }
        }
    }
}

// P2: per-block local exclusive scan; block prefix = reduce of raw bsum[0..b) (nsb<=128)
__global__ __launch_bounds__(256) void k_scanC(const unsigned* __restrict__ M,
        const unsigned* __restrict__ bsum, unsigned* __restrict__ Msc, int n, int nsb){
    __shared__ unsigned lds[4];
    __shared__ unsigned ps[2];
    int t = threadIdx.x;
    unsigned pv = (t < nsb && t < (int)blockIdx.x) ? bsum[t] : 0u;
    #pragma unroll
    for(int o=1;o<64;o<<=1) pv += __shfl_xor(pv,o);
    if((t&63)==0 && t<128) ps[t>>6]=pv;
    int base = blockIdx.x*4096 + t*16;
    unsigned v[16]; unsigned tsum=0;
    #pragma unroll
    for(int k=0;k<16;++k){ int i=base+k; v[k]=(i<n)?M[i]:0u; tsum+=v[k]; }
    unsigned x=tsum;
    #pragma unroll
    for(int o=1;o<64;o<<=1){ unsigned y=__shfl_up(x,(unsigned)o); if((t&63)>=o) x+=y; }
    if((t&63)==63) lds[t>>6]=x;
    __syncthreads();
    unsigned run = ps[0]+ps[1];
    for(int w=0;w<(t>>6);++w) run += lds[w];
    run += (x - tsum);
    #pragma unroll
    for(int k=0;k<16;++k){ int i=base+k; if(i<n) Msc[i]=run; run+=v[k]; }
}

// P3: bucket-partition edges; per-edge exp-weight computed here.
// 2 edges/thread via int2 loads (E and CHUNK even -> pair-aligned ranges).
__global__ __launch_bounds__(256) void k_bscatter(const int* __restrict__ src,
        const int* __restrict__ dst, const unsigned* __restrict__ Msc,
        const float* __restrict__ ss, const float* __restrict__ sdv,
        uint2* __restrict__ ew, int E, int NB, int CHUNK){
    __shared__ unsigned hoff[1600];
    int blk = blockIdx.x, NBLKg = gridDim.x;
    for(int i=threadIdx.x;i<NB;i+=256) hoff[i] = Msc[(size_t)i*NBLKg + blk];
    __syncthreads();
    int s0 = blk*CHUNK;
    int e1 = s0+CHUNK < E ? s0+CHUNK : E;
    for(int i=s0+(int)threadIdx.x*2; i<e1; i+=512){
        int2 s2 = *(const int2*)(src + i);
        int2 d2 = *(const int2*)(dst + i);
        float a0 = ss[s2.x], a1 = ss[s2.y];
        float b0 = sdv[d2.x], b1 = sdv[d2.y];
        float w0 = __expf(leaky(a0 + b0));
        float w1 = __expf(leaky(a1 + b1));
        unsigned p0 = atomicAdd(&hoff[((unsigned)d2.x)>>6], 1u);
        ew[p0] = make_uint2(((unsigned)s2.x<<6)|((unsigned)d2.x&63u), __float_as_uint(w0));
        unsigned p1 = atomicAdd(&hoff[((unsigned)d2.y)>>6], 1u);
        ew[p1] = make_uint2(((unsigned)s2.y<<6)|((unsigned)d2.y&63u), __float_as_uint(w1));
    }
}

__device__ __forceinline__ void fma8(float* acc, uint4 u, float w){
    acc[0]=fmaf(w,__uint_as_float(u.x<<16),acc[0]);
    acc[1]=fmaf(w,__uint_as_float(u.x&0xffff0000u),acc[1]);
    acc[2]=fmaf(w,__uint_as_float(u.y<<16),acc[2]);
    acc[3]=fmaf(w,__uint_as_float(u.y&0xffff0000u),acc[3]);
    acc[4]=fmaf(w,__uint_as_float(u.z<<16),acc[4]);
    acc[5]=fmaf(w,__uint_as_float(u.z&0xffff0000u),acc[5]);
    acc[6]=fmaf(w,__uint_as_float(u.w<<16),acc[6]);
    acc[7]=fmaf(w,__uint_as_float(u.w&0xffff0000u),acc[7]);
}

// Fused fine-sort + gather: block = one 64-dst bucket. Counting-sort into LDS,
// then per-dst weighted gather (4 edges/iter, 16 lanes/edge).
__global__ __launch_bounds__(256) void k_gfine(const uint2* __restrict__ ew,
        const unsigned* __restrict__ Msc, const unsigned short* __restrict__ Hp,
        float* __restrict__ out, int N, int NB, int E){
    __shared__ uint2 sed[CAP+16];
    __shared__ unsigned cA[64], cB[64], loff[64];
    __shared__ unsigned begS, endS;
    const int b = blockIdx.x;
    const int dbase = b<<6;
    const int tid = threadIdx.x;
    if(tid==0){
        begS = Msc[(size_t)b*256];
        endS = (b+1 < NB) ? Msc[(size_t)(b+1)*256] : (unsigned)E;
    }
    if(tid<64){ cA[tid]=0u; cB[tid]=0u; }
    __syncthreads();
    const unsigned beg = begS;
    const unsigned size = endS - begS;
    const int wv = tid>>6, l = tid&63;
    const int g = l>>4, t = l&15;
    const unsigned toff = (unsigned)t*16u;

    if(size <= CAP){
        for(unsigned i=tid; i<size; i+=256)
            atomicAdd(&cA[ew[beg+i].x & 63u], 1u);
        __syncthreads();
        if(tid<64){
            unsigned c = cA[tid];
            unsigned x = c;
            #pragma unroll
            for(int o=1;o<64;o<<=1){ unsigned y = __shfl_up(x,(unsigned)o); if(tid>=o) x += y; }
            loff[tid] = x - c;
        }
        __syncthreads();
        for(unsigned i=tid; i<size; i+=256){
            uint2 p = ew[beg+i];
            unsigned dl = p.x & 63u;
            unsigned r = atomicAdd(&cB[dl], 1u);
            sed[loff[dl]+r] = make_uint2(p.x>>6, p.y);
        }
        for(unsigned i=size+tid; i<size+16u; i+=256) sed[i] = make_uint2(0u,0u);
        __syncthreads();
        #pragma unroll 1
        for(int i=0;i<16;++i){
            int dl = i*4 + wv;
            int d = dbase + dl;
            if(d >= N) continue;                      // wave-uniform
            unsigned kb = loff[dl], ke = kb + cB[dl];
            float acc[8];
            #pragma unroll
            for(int j=0;j<8;++j) acc[j]=0.f;
            float den = 0.f;
            unsigned e = kb + g;
            uint2 p0 = sed[e];
            uint4 u0 = *(const uint4*)((const char*)Hp + ((p0.x<<8) + toff));
            uint2 p1 = sed[e+4];
            uint4 u1 = *(const uint4*)((const char*)Hp + ((p1.x<<8) + toff));
            while(e < ke){
                float w0 = __uint_as_float(p0.y);
                fma8(acc, u0, w0);
                p0 = sed[e+8];
                u0 = *(const uint4*)((const char*)Hp + ((p0.x<<8) + toff));
                float w1 = (e+4 < ke) ? __uint_as_float(p1.y) : 0.f;
                fma8(acc, u1, w1);
                p1 = sed[e+12];
                u1 = *(const uint4*)((const char*)Hp + ((p1.x<<8) + toff));
                den += w0 + w1;
                e += 8;
            }
            #pragma unroll
            for(int j=0;j<8;++j){
                acc[j] += __shfl_xor(acc[j],16);
                acc[j] += __shfl_xor(acc[j],32);
            }
            den += __shfl_xor(den,16);
            den += __shfl_xor(den,32);
            float inv = 1.f/(den + 1e-9f);
            int c = g*32 + t;
            out[(size_t)d*D + c]      = acc[g*2]  * inv;
            out[(size_t)d*D + c + 16] = acc[g*2+1]* inv;
        }
    } else {
        #pragma unroll 1
        for(int i=0;i<16;++i){
            int dl = i*4 + wv;
            int d = dbase + dl;
            if(d >= N) continue;
            float acc[8];
            #pragma unroll
            for(int j=0;j<8;++j) acc[j]=0.f;
            float den = 0.f;
            for(unsigned e2 = beg + (unsigned)g; e2 < beg + size; e2 += 4){
                uint2 p = ew[e2];
                if((int)(p.x & 63u) != dl) continue;
                float w = __uint_as_float(p.y);
                uint4 u = *(const uint4*)((const char*)Hp + (((p.x>>6)<<8) + toff));
                fma8(acc, u, w);
                den += w;
            }
            #pragma unroll
            for(int j=0;j<8;++j){
                acc[j] += __shfl_xor(acc[j],16);
                acc[j] += __shfl_xor(acc[j],32);
            }
            den += __shfl_xor(den,16);
            den += __shfl_xor(den,32);
            float inv = 1.f/(den + 1e-9f);
            int c = g*32 + t;
            out[(size_t)d*D + c]      = acc[g*2]  * inv;
            out[(size_t)d*D + c + 16] = acc[g*2+1]* inv;
        }
    }
}

// out = leaky(f + h + (f*h)@W2^T + b2), in place on out; W2 (bf16) staged in LDS
__global__ __launch_bounds__(256) void k_final(const float* __restrict__ F,
        const unsigned short* __restrict__ W2b, const float* __restrict__ b2,
        float* __restrict__ out, int N, int GF){
    __shared__ __align__(16) unsigned short Wlds[17408];
    #pragma unroll
    for(int k=0;k<8;++k){
        int idx = ((int)threadIdx.x + k*256)*8;
        int row = idx >> 7, col = idx & 127;
        *(short8*)(&Wlds[row*136 + col]) = *(const short8*)(W2b + idx);
    }
    __syncthreads();
    const int lane = threadIdx.x & 63, wv = threadIdx.x>>6;
    const int t = lane & 15, g = lane >> 4;
    float bb[8];
    #pragma unroll
    for(int j=0;j<8;++j) bb[j] = b2[j*16+t];
    const int Mt = (N+15)>>4;
    for(int rt = (int)blockIdx.x*4 + wv; rt < Mt; rt += GF*4){
        int row = rt*16 + t; if(row>=N) row = N-1;
        const float* fr = F   + (size_t)row*D + g*8;
        const float* hr = out + (size_t)row*D + g*8;
        f32x4 acc[8];
        #pragma unroll
        for(int j=0;j<8;++j) acc[j] = (f32x4){0.f,0.f,0.f,0.f};
        #pragma unroll
        for(int kk=0;kk<4;++kk){
            f32x4 flo = *(const f32x4*)(fr + kk*32);
            f32x4 fhi = *(const f32x4*)(fr + kk*32 + 4);
            f32x4 hlo = *(const f32x4*)(hr + kk*32);
            f32x4 hhi = *(const f32x4*)(hr + kk*32 + 4);
            short8 af = pack8m(flo*hlo, fhi*hhi);
            #pragma unroll
            for(int j=0;j<8;++j){
                short8 wfj = *(const short8*)(&Wlds[(j*16+t)*136 + kk*32 + g*8]);
                acc[j] = __builtin_amdgcn_mfma_f32_16x16x32_bf16(af, wfj, acc[j], 0,0,0);
            }
        }
        #pragma unroll
        for(int r=0;r<4;++r){
            int rr = rt*16 + g*4 + r;
            if(rr < N){
                #pragma unroll
                for(int j=0;j<8;++j){
                    int c = j*16 + t;
                    float f = F[(size_t)rr*D + c];
                    float h = out[(size_t)rr*D + c];
                    out[(size_t)rr*D + c] = leaky(f + h + acc[j][r] + bb[j]);
                }
            }
        }
    }
}

extern "C" void kernel_launch(void* const* d_in, const int* in_sizes, int n_in,
                              void* d_out, int out_size, void* d_ws, size_t ws_size,
                              hipStream_t stream) {
    const int*   idx  = (const int*)  d_in[0];   // (2,E)
    const float* F    = (const float*)d_in[1];   // (N,128)
    const float* Waw  = (const float*)d_in[3];
    const float* Wab  = (const float*)d_in[4];
    const float* W1w  = (const float*)d_in[5];
    const float* W1b  = (const float*)d_in[6];
    const float* W2w  = (const float*)d_in[7];
    const float* W2b  = (const float*)d_in[8];
    const float* a    = (const float*)d_in[9];
    float* out = (float*)d_out;

    const int E = in_sizes[0]/2;
    const int N = in_sizes[1]/D;
    const int* srcp = idx;
    const int* dstp = idx + E;

    const int NBLK = 256;
    const int CHUNK = (((E + NBLK - 1)/NBLK) + 1) & ~1;    // even -> pair-aligned
    const int NB = (N + 63)/64;            // coarse buckets (<=1600)
    const int NT = NB*NBLK;
    const int NSB = (NT + 4095)/4096;      // <=100 by construction

    uint2*    ew   = (uint2*)d_ws;                          // E
    unsigned short* Hp  = (unsigned short*)(ew + E);        // N*128 bf16
    unsigned short* W1c = Hp + (size_t)N*D;                 // 16384
    unsigned short* W2c = W1c + 16384;                      // 16384
    float*    ss   = (float*)(W2c + 16384);                 // N
    float*    sd   = ss + N;                                // N
    float*    v    = sd + N;                                // 320
    unsigned* M    = (unsigned*)(v + 320);                  // NT
    unsigned* Msc  = M + NT;                                // NT+2
    unsigned* bsum = Msc + NT + 2;                          // NSB

    const int GT = 512;
    const int GF = 512;

    k_prep    <<<66, 256, 0, stream>>>(Waw, Wab, a, v, W1w, W2w, W1c, W2c, bsum, NSB);
    k_msgscal <<<GT+NBLK, 256, 0, stream>>>(F, W1c, W1b, v, Hp, ss, sd, N,
                                            dstp, M, bsum, E, GT, CHUNK, NB, NSB);
    k_scanC   <<<NSB, 256, 0, stream>>>(M, bsum, Msc, NT, NSB);
    k_bscatter<<<NBLK, 256, 0, stream>>>(srcp, dstp, Msc, ss, sd, ew, E, NB, CHUNK);
    k_gfine   <<<NB, 256, 0, stream>>>(ew, Msc, Hp, out, N, NB, E);
    k_final   <<<GF, 256, 0, stream>>>(F, W2c, W2b, out, N, GF);
}